// Round 12
// baseline (1307.439 us; speedup 1.0000x reference)
//
#include <hip/hip_runtime.h>
#include <hip/hip_bf16.h>
#include <cstdint>

#define N_NODES 20000
#define N_EDGES 100000
#define WALK 4
#define FDIM 256
#define HID 64
#define NHEAD 8
#define HR 512
#define OUTD 16

typedef __attribute__((ext_vector_type(8))) short bf16x8;
typedef __attribute__((ext_vector_type(8))) unsigned short u16x8;
typedef __attribute__((ext_vector_type(4))) float f32x4;

__device__ __forceinline__ float b2f(unsigned short u){
  union{float f; unsigned u;} x; x.u = ((unsigned)u)<<16; return x.f;
}
__device__ __forceinline__ unsigned short f2b(float f){
  union{float f; unsigned u;} x; x.f = f;
  unsigned r = x.u + 0x7FFFu + ((x.u>>16)&1u);
  return (unsigned short)(r>>16);
}
__device__ __forceinline__ float sigmoidf_(float v){ return 1.0f/(1.0f+__expf(-v)); }
__device__ __forceinline__ float tanh_c(float v){
  v = fminf(fmaxf(v, -15.f), 15.f);
  const float t2 = __expf(2.0f*v);
  return (t2 - 1.0f) / (t2 + 1.0f);
}

__device__ __forceinline__ void gload16(const void* g, void* l){
  __builtin_amdgcn_global_load_lds(
      (const __attribute__((address_space(1))) void*)(g),
      (__attribute__((address_space(3))) void*)(l),
      16, 0, 0);
}

__device__ __forceinline__ f32x4 mfma16(bf16x8 a, bf16x8 b, f32x4 c){
  return __builtin_amdgcn_mfma_f32_16x16x32_bf16(a, b, c, 0, 0, 0);
}

// ---------------- emb = bf16(x @ W_mlp.T + b_mlp)  (20000x64, linear) ----------------
__launch_bounds__(256)
__global__ void emb_kernel(const float* __restrict__ x,
                           const float* __restrict__ Wm,
                           const float* __restrict__ bm,
                           unsigned short* __restrict__ emb_bf)
{
  __shared__ float xs[4][FDIM];
  const int tid = threadIdx.x;
  const int node0 = blockIdx.x * 4;
  {
    const int row = tid >> 6;
    const int k4  = (tid & 63) * 4;
    *reinterpret_cast<float4*>(&xs[row][k4]) =
      *reinterpret_cast<const float4*>(&x[(size_t)(node0+row)*FDIM + k4]);
  }
  __syncthreads();
  const int nn = tid >> 6, c = tid & 63;
  float acc = bm[c];
  const float* wr = &Wm[c*FDIM];
  #pragma unroll 8
  for (int k=0;k<FDIM;k+=4){
    const float4 w = *reinterpret_cast<const float4*>(&wr[k]);
    acc += xs[nn][k]*w.x + xs[nn][k+1]*w.y + xs[nn][k+2]*w.z + xs[nn][k+3]*w.w;
  }
  emb_bf[(size_t)(node0+nn)*HID + c] = f2b(acc);
}

// ---------------- weight prep (bf16, gate-BLOCKED rows, chunk-swizzle) ----------------
// WhhP: [8 db][192 r][512 k]; row r -> W row G=(r>>6)*512 + db*64 + (r&63);
// position chunk c holds logical chunk c^(r&7) per 64-k group. WihP: [8][192][64] same.
// WembP: [64 o][512 k] keyed by o&7.
__launch_bounds__(256)
__global__ void prep_kernel(const float* __restrict__ Whh,
                            const float* __restrict__ Wih,
                            const float* __restrict__ Wemb,
                            unsigned short* __restrict__ WhhP,
                            unsigned short* __restrict__ WihP,
                            unsigned short* __restrict__ WembP)
{
  const int t = blockIdx.x*256 + threadIdx.x;
  if (t < 8*192*512){
    const int k = t & 511;
    const int r = (t >> 9) % 192;
    const int db = t / 98304;
    const int G = (r>>6)*HR + db*64 + (r&63);
    const int kg = k >> 6, kw = k & 63;
    const int c = kw >> 3, o = kw & 7;
    const int ksrc = (kg<<6) + (((c ^ (r&7)) << 3) | o);
    WhhP[t] = f2b(Whh[(size_t)G*HR + ksrc]);
  }
  if (t < 8*192*64){
    const int k = t & 63;
    const int r = (t >> 6) % 192;
    const int db = t / 12288;
    const int G = (r>>6)*HR + db*64 + (r&63);
    const int c = k >> 3, o = k & 7;
    const int ksrc = (((c ^ (r&7)) << 3) | o);
    WihP[t] = f2b(Wih[(size_t)G*HID + ksrc]);
  }
  if (t < 64*512){
    const int k = t & 511;
    const int o = t >> 9;
    const int kg = k >> 6, kw = k & 63;
    const int c = kw >> 3, off = kw & 7;
    const int ksrc = (kg<<6) + (((c ^ (o&7)) << 3) | off);
    WembP[t] = f2b(Wemb[(size_t)o*HR + ksrc]);
  }
}

// ---------------- xg: per-node x-gates -> xnP (n-gate + b_ih_n) and h1n ---------------
__launch_bounds__(256)
__global__ void xg_kernel(const unsigned short* __restrict__ emb_bf,
                          const unsigned short* __restrict__ WihP,
                          const float* __restrict__ b_ih,
                          const float* __restrict__ b_hh,
                          unsigned short* __restrict__ xnP,
                          unsigned short* __restrict__ h1n)
{
  __shared__ __align__(16) unsigned short As[128*64];
  __shared__ __align__(16) unsigned short Bs[192*64];
  const int tid = threadIdx.x, lane = tid & 63, w = tid >> 6;
  const int tx = lane & 15, ty = lane >> 4;
  const int n0 = blockIdx.x * 128;
  const int db = blockIdx.y;

  #pragma unroll
  for (int j=0;j<4;++j){
    const int flat = j*256 + tid;
    const int row = flat >> 3, c = flat & 7;
    int n = n0 + row; if (n > N_NODES-1) n = N_NODES-1;
    gload16(emb_bf + ((size_t)n*HID + ((c ^ (row&7))<<3)), (char*)As + flat*16);
  }
  #pragma unroll
  for (int j=0;j<6;++j){
    const int flat = j*256 + tid;
    const int row = flat >> 3, c = flat & 7;
    gload16(WihP + ((size_t)(db*192 + row)*HID + c*8), (char*)Bs + flat*16);
  }
  __syncthreads();

  f32x4 acc[2][12];
  #pragma unroll
  for (int m=0;m<2;++m)
    #pragma unroll
    for (int f=0;f<12;++f) acc[m][f] = (f32x4)(0.f);

  auto readFrag = [&](const unsigned short* base, int row, int kk)->bf16x8{
    const int chunk = (kk<<2) + ty;
    return *reinterpret_cast<const bf16x8*>(
        reinterpret_cast<const char*>(base) + (row<<7) + ((chunk ^ (row&7))<<4));
  };
  #pragma unroll
  for (int kk=0; kk<2; ++kk){
    const bf16x8 a0 = readFrag(As, w*32 + tx, kk);
    const bf16x8 a1 = readFrag(As, w*32 + 16 + tx, kk);
    #pragma unroll
    for (int nf=0; nf<12; ++nf){
      const bf16x8 b = readFrag(Bs, nf*16 + tx, kk);
      acc[0][nf] = mfma16(a0, b, acc[0][nf]);
      acc[1][nf] = mfma16(a1, b, acc[1][nf]);
    }
  }

  #pragma unroll
  for (int m=0;m<2;++m){
    #pragma unroll
    for (int reg=0; reg<4; ++reg){
      const int row = w*32 + m*16 + ty*4 + reg;
      const int n = n0 + row;
      if (n < N_NODES){
        #pragma unroll
        for (int fr=0; fr<4; ++fr){
          const int d6 = fr*16 + tx;
          const int dG = db*64 + d6;
          const float xr = acc[m][fr][reg]   + b_ih[dG];
          const float xz = acc[m][4+fr][reg] + b_ih[HR+dG];
          const float xn = acc[m][8+fr][reg] + b_ih[2*HR+dG];
          xnP[((size_t)db*N_NODES + n)*64 + d6] = f2b(xn);
          const float r = sigmoidf_(xr + b_hh[dG]);
          const float z = sigmoidf_(xz + b_hh[HR+dG]);
          const float nn = tanh_c(xn + r*b_hh[2*HR+dG]);
          h1n[(size_t)n*HR + dG] = f2b((1.0f - z)*nn);
        }
      }
    }
  }
}

// ---------------- GRU step via MFMA: R9 core, BM=256 (8 waves, 56KB, 2 blocks/CU) -----
// BM=256 edges, BN=192 (gate-blocked: nf 0..3=r, 4..7=z, 8..11=n), BK=64.
// kt 0..7 = h (K=512), kt 8 = x (gathered emb; n-frags skipped, xn from xnP).
// Wave w in [0,8) owns rows [w*32,+32) (2 Mf), ALL 12 Nf (complete output rows ->
// coalesced epilogue writes; R10 lesson: splitting rows across waves amplifies WRITE).
// Halves blocks/CU vs R9 -> halves total barrier-drain events.
template<int STEP, bool SCORE>
__launch_bounds__(512, 2)
__global__ void gru_mfma(const unsigned short* __restrict__ emb_bf,
                         const int* __restrict__ idx,
                         const unsigned short* __restrict__ h_in,  // STEP==1: h1n per-node linear; else per-edge swizzled
                         unsigned short* __restrict__ h_out,
                         const unsigned short* __restrict__ WhhP,
                         const unsigned short* __restrict__ WihP,
                         const unsigned short* __restrict__ xnP,
                         const float* __restrict__ b_ih,
                         const float* __restrict__ b_hh,
                         const float* __restrict__ attn,
                         float* __restrict__ a_buf,
                         unsigned int* __restrict__ mmax)
{
  constexpr bool GATHER = (STEP == 1);
  __shared__ __align__(16) unsigned short As[256*64];   // 32 KB
  __shared__ __align__(16) unsigned short Bs[192*64];   // 24 KB

  const int tid = threadIdx.x, lane = tid & 63, w = tid >> 6;
  const int tx = lane & 15, ty = lane >> 4;

  const int bid = blockIdx.x;
  const int sid = (bid & 7)*391 + (bid >> 3);   // bijective XCD swizzle (3128 = 8*391)
  const int et = sid >> 3;
  const int db = sid & 7;
  const int e0 = et * 256;

  // preload idx-derived nodes (no vmem address work inside the K-loop)
  int eS[4], nH[4], nX[4];
  #pragma unroll
  for (int j=0;j<4;++j){
    int e = e0 + ((j*512 + tid) >> 3);
    if (e > N_EDGES-1) e = N_EDGES-1;
    eS[j] = e;
    nX[j] = idx[e*WALK + STEP];
    nH[j] = GATHER ? idx[e*WALK] : 0;
  }

  f32x4 acc[2][12];
  #pragma unroll
  for (int m=0;m<2;++m)
    #pragma unroll
    for (int f=0;f<12;++f) acc[m][f] = (f32x4)(0.f);

  auto stageA = [&](int kt){
    #pragma unroll
    for (int j=0;j<4;++j){
      const int flat = j*512 + tid;
      const int row = flat >> 3, c = flat & 7;
      const unsigned short* src;
      if (kt == 8){
        src = emb_bf + ((size_t)nX[j]*HID + ((c ^ (row&7)) << 3));
      } else if (GATHER){
        src = h_in + ((size_t)nH[j]*HR + kt*64 + ((c ^ (row&7)) << 3));
      } else {
        src = h_in + ((size_t)eS[j]*HR + kt*64 + c*8);
      }
      gload16(src, (char*)As + flat*16);
    }
  };
  auto stageB = [&](int kt){
    #pragma unroll
    for (int j=0;j<3;++j){
      const int flat = j*512 + tid;
      const int row = flat >> 3, c = flat & 7;
      const unsigned short* src = (kt < 8)
        ? WhhP + ((size_t)(db*192 + row)*HR + kt*64 + c*8)
        : WihP + ((size_t)(db*192 + row)*HID + c*8);
      gload16(src, (char*)Bs + flat*16);
    }
  };
  auto readFrag = [&](const unsigned short* base, int row, int kk)->bf16x8{
    const int chunk = (kk<<2) + ty;
    return *reinterpret_cast<const bf16x8*>(
        reinterpret_cast<const char*>(base) + (row<<7) + ((chunk ^ (row&7))<<4));
  };

  stageA(0); stageB(0);

  #pragma unroll
  for (int kt=0; kt<9; ++kt){
    __syncthreads();            // drains vmcnt for the staged tile (compiler-inserted)
    #pragma unroll
    for (int kk=0; kk<2; ++kk){
      const bf16x8 a0 = readFrag(As, w*32 + tx, kk);
      const bf16x8 a1 = readFrag(As, w*32 + 16 + tx, kk);
      #pragma unroll
      for (int nf=0; nf<12; ++nf){
        if (kt == 8 && nf >= 8) continue;     // x-tile: skip n-gate (xn comes from xnP)
        const bf16x8 b = readFrag(Bs, nf*16 + tx, kk);
        acc[0][nf] = mfma16(a0, b, acc[0][nf]);
        acc[1][nf] = mfma16(a1, b, acc[1][nf]);
      }
    }
    if (kt < 8){
      __syncthreads();
      stageA(kt+1); stageB(kt+1);
    }
  }

  // ---- epilogue: pure-register gate fusion (wave owns full rows -> coalesced writes) --
  float bir[4], biz[4], bhn[4], atv[4];
  #pragma unroll
  for (int fr=0; fr<4; ++fr){
    const int dG = db*64 + fr*16 + tx;
    bir[fr] = b_ih[dG]      + b_hh[dG];
    biz[fr] = b_ih[HR+dG]   + b_hh[HR+dG];
    bhn[fr] = b_hh[2*HR+dG];
    atv[fr] = SCORE ? attn[dG] : 0.f;
  }

  #pragma unroll
  for (int m=0;m<2;++m){
    #pragma unroll
    for (int reg=0; reg<4; ++reg){
      const int row = w*32 + m*16 + ty*4 + reg;
      const int e = e0 + row;
      float sp = 0.f;
      if (e < N_EDGES){
        const int nodeS = idx[e*WALK + STEP];
        const int nodeH = GATHER ? idx[e*WALK] : 0;
        #pragma unroll
        for (int fr=0; fr<4; ++fr){
          const int d6 = fr*16 + tx;
          const int dG = db*64 + d6;
          const float xn = b2f(xnP[((size_t)db*N_NODES + nodeS)*64 + d6]);
          float hold;
          if (GATHER) hold = b2f(h_in[(size_t)nodeH*HR + dG]);
          else        hold = b2f(h_in[(size_t)e*HR + db*64 + (((d6>>3) ^ (e&7))<<3) + (d6&7)]);
          const float r  = sigmoidf_(acc[m][fr][reg]   + bir[fr]);
          const float z  = sigmoidf_(acc[m][4+fr][reg] + biz[fr]);
          const float nn = tanh_c(xn + r*(acc[m][8+fr][reg] + bhn[fr]));
          const float hv = (1.0f - z)*nn + z*hold;
          h_out[(size_t)e*HR + db*64 + (((d6>>3) ^ (e&7))<<3) + (d6&7)] = f2b(hv);
          if (SCORE) sp += hv * atv[fr];
        }
      }
      if (SCORE){
        sp += __shfl_xor(sp, 1);
        sp += __shfl_xor(sp, 2);
        sp += __shfl_xor(sp, 4);
        sp += __shfl_xor(sp, 8);
        if (tx == 0 && e < N_EDGES){
          // fused leaky-relu + segment max (score2_kernel folded in)
          const float a = sp > 0.f ? sp : 0.01f*sp;
          a_buf[e*NHEAD + db] = a;
          const int dst = idx[e*WALK + 3];
          union{float f; unsigned u;} xx; xx.f = a;
          const unsigned key = (xx.u & 0x80000000u) ? ~xx.u : (xx.u | 0x80000000u);
          atomicMax(&mmax[dst*NHEAD + db], key);
        }
      }
    }
  }
}

// ---------------- exp(a-m) + segment sum ----------------
__launch_bounds__(256)
__global__ void ea_kernel(const int* __restrict__ idx,
                          float* __restrict__ a_buf,
                          const unsigned int* __restrict__ mmax,
                          float* __restrict__ ssum)
{
  const int flat = blockIdx.x*256 + threadIdx.x;
  const int e = flat >> 3, h = flat & 7;
  const int dst = idx[e*WALK + 3];
  const unsigned key = mmax[dst*NHEAD + h];
  union{float f; unsigned u;} x;
  x.u = (key & 0x80000000u) ? (key & 0x7FFFFFFFu) : ~key;
  const float ea = __expf(a_buf[flat] - x.f);
  a_buf[flat] = ea;
  atomicAdd(&ssum[dst*NHEAD + h], ea);
}

// ---------------- z[e] = (hT[e]*alpha) @ Wemb.T ; zacc[dst] += z[e] -------------------
// alpha computed inline: alpha = ea[e,h] / ssum[dst,h]
__launch_bounds__(256)
__global__ void z_kernel(const unsigned short* __restrict__ hT,
                         const int* __restrict__ idx,
                         const float* __restrict__ ea_buf,
                         const float* __restrict__ ssum,
                         const unsigned short* __restrict__ WembP,
                         float* __restrict__ zacc)
{
  __shared__ __align__(16) char zs[40960];  // Az 32768 + Bz 8192
  char* Az = zs;
  char* Bz = zs + 32768;
  const int tid = threadIdx.x;
  const int lane = tid & 63;
  const int w = tid >> 6;
  const int e0 = blockIdx.x * 256;

  int ej[8], dstj[8];
  #pragma unroll
  for (int j=0;j<8;++j){
    int e = e0 + ((j*256 + tid) >> 3);
    if (e > N_EDGES-1) e = N_EDGES-1;
    ej[j] = e;
    dstj[j] = idx[e*WALK + 3];
  }

  f32x4 acc[4][4];
  #pragma unroll
  for (int m=0;m<4;++m)
    #pragma unroll
    for (int f=0;f<4;++f) acc[m][f] = (f32x4)(0.f);

  auto readFrag = [&](const char* base, int row, int kk)->bf16x8{
    const int chunk = (kk<<2) + (lane>>4);
    return *reinterpret_cast<const bf16x8*>(base + (row<<7) + ((chunk ^ (row&7))<<4));
  };

  #pragma unroll 1
  for (int kt=0; kt<8; ++kt){
    __syncthreads();
    #pragma unroll
    for (int j=0;j<8;++j){
      const int flat = j*256 + tid;
      const int e = ej[j];
      const u16x8 hv = *reinterpret_cast<const u16x8*>(hT + (size_t)e*HR + kt*64 + (flat&7)*8);
      const float al = ea_buf[e*NHEAD + kt] / ssum[dstj[j]*NHEAD + kt];
      union { bf16x8 v; unsigned short s[8]; } o;
      #pragma unroll
      for (int i=0;i<8;++i) o.s[i] = f2b(b2f(hv[i]) * al);
      *reinterpret_cast<bf16x8*>(Az + flat*16) = o.v;
    }
    #pragma unroll
    for (int j=0;j<2;++j){
      const int flat = j*256 + tid;
      const int row = flat >> 3, c = flat & 7;
      gload16(WembP + ((size_t)row*HR + kt*64 + c*8), Bz + ((j*256 + w*64)<<4));
    }
    __syncthreads();
    #pragma unroll
    for (int kk=0; kk<2; ++kk){
      bf16x8 a_[4];
      #pragma unroll
      for (int mf=0; mf<4; ++mf)
        a_[mf] = readFrag(Az, w*64 + mf*16 + (lane&15), kk);
      #pragma unroll
      for (int nf=0; nf<4; ++nf){
        const bf16x8 b_ = readFrag(Bz, nf*16 + (lane&15), kk);
        #pragma unroll
        for (int mf=0; mf<4; ++mf)
          acc[mf][nf] = mfma16(a_[mf], b_, acc[mf][nf]);
      }
    }
  }

  #pragma unroll
  for (int mf=0; mf<4; ++mf){
    #pragma unroll
    for (int reg=0; reg<4; ++reg){
      const int row = w*64 + mf*16 + ((lane>>4)<<2) + reg;
      const int e = e0 + row;
      if (e < N_EDGES){
        const int dst = idx[e*WALK + 3];
        #pragma unroll
        for (int nf=0; nf<4; ++nf){
          const int o = nf*16 + (lane&15);
          atomicAdd(&zacc[(size_t)dst*64 + o], acc[mf][nf][reg]);
        }
      }
    }
  }
}

// ---------------- out = (zacc + b_emb) @ W_last.T + b_last ----------------
__launch_bounds__(256)
__global__ void out2_kernel(const float* __restrict__ zacc,
                            const float* __restrict__ b_emb,
                            const float* __restrict__ W_last,
                            const float* __restrict__ b_last,
                            float* __restrict__ out)
{
  const int flat = blockIdx.x*256 + threadIdx.x;
  if (flat >= N_NODES*OUTD) return;
  const int n = flat >> 4, o = flat & 15;
  float s = b_last[o];
  const float* zr = &zacc[(size_t)n*64];
  const float* wl = &W_last[o*64];
  #pragma unroll
  for (int k=0;k<64;++k) s += (zr[k] + b_emb[k]) * wl[k];
  out[(size_t)n*OUTD + o] = s;
}

// ---------------- launch ----------------
extern "C" void kernel_launch(void* const* d_in, const int* in_sizes, int n_in,
                              void* d_out, int out_size, void* d_ws, size_t ws_size,
                              hipStream_t stream)
{
  (void)in_sizes; (void)n_in; (void)out_size; (void)ws_size;
  const float* x      = (const float*)d_in[0];
  const float* W_mlp  = (const float*)d_in[1];
  const float* b_mlp  = (const float*)d_in[2];
  const float* W_ih   = (const float*)d_in[3];
  const float* W_hh   = (const float*)d_in[4];
  const float* b_ih   = (const float*)d_in[5];
  const float* b_hh   = (const float*)d_in[6];
  const float* attn   = (const float*)d_in[7];
  const float* W_emb  = (const float*)d_in[8];
  const float* b_emb  = (const float*)d_in[9];
  const float* W_last = (const float*)d_in[10];
  const float* b_last = (const float*)d_in[11];
  const int*   idx    = (const int*)d_in[12];
  float* out = (float*)d_out;

  char* ws = (char*)d_ws;
  unsigned short* WhhP   = (unsigned short*)(ws + 0);            //   1,572,864
  unsigned short* WihP   = (unsigned short*)(ws + 1572864);      //     196,608
  unsigned short* WembP  = (unsigned short*)(ws + 1769472);      //      65,536
  unsigned short* emb_bf = (unsigned short*)(ws + 1835008);      //   2,560,000
  unsigned short* xnP    = (unsigned short*)(ws + 4395008);      //  20,480,000
  float*          a_buf  = (float*)(ws + 24875008);              //   3,200,000
  unsigned int*   mmax   = (unsigned int*)(ws + 28075008);       //     640,000
  float*          ssum   = (float*)(ws + 28715008);              //     640,000
  float*          zacc   = (float*)(ws + 29355008);              //   5,120,000
  unsigned short* h_a    = (unsigned short*)(ws + 34475008);     // 102,400,000
  unsigned short* h_b    = (unsigned short*)(ws + 136875008);    // 102,400,000
  unsigned short* h1n    = h_b;  // alias: h1n dead before gru step 2 writes h_b
  // total = 239,275,008 B

  // zero mmax + ssum + zacc (contiguous 6.4 MB); a_buf written unconditionally by gru
  hipMemsetAsync(mmax, 0, 6400000, stream);

  prep_kernel<<<3072, 256, 0, stream>>>(W_hh, W_ih, W_emb, WhhP, WihP, WembP);
  emb_kernel<<<N_NODES/4, 256, 0, stream>>>(x, W_mlp, b_mlp, emb_bf);

  dim3 xgrid((N_NODES + 127)/128, 8);   // 157 x 8
  xg_kernel<<<xgrid, 256, 0, stream>>>(emb_bf, WihP, b_ih, b_hh, xnP, h1n);

  const int NWG = 391*8;  // 3128 blocks: 391 edge-tiles (256 each) x 8 d-blocks
  gru_mfma<1,false><<<NWG, 512, 0, stream>>>(emb_bf, idx, h1n, h_a, WhhP, WihP, xnP, b_ih, b_hh, attn, a_buf, mmax);
  gru_mfma<2,false><<<NWG, 512, 0, stream>>>(emb_bf, idx, h_a, h_b, WhhP, WihP, xnP, b_ih, b_hh, attn, a_buf, mmax);
  gru_mfma<3,true ><<<NWG, 512, 0, stream>>>(emb_bf, idx, h_b, h_a, WhhP, WihP, xnP, b_ih, b_hh, attn, a_buf, mmax);
  // hT (swizzled) in h_a; leaky scores in a_buf; segment max in mmax

  ea_kernel<<<N_EDGES*NHEAD/256, 256, 0, stream>>>(idx, a_buf, mmax, ssum);
  z_kernel<<<391, 256, 0, stream>>>(h_a, idx, a_buf, ssum, WembP, zacc);
  out2_kernel<<<(N_NODES*OUTD+255)/256, 256, 0, stream>>>(zacc, b_emb, W_last, b_last, out);
}

// Round 14
// 1170.487 us; speedup vs baseline: 1.1170x; 1.1170x over previous
//
#include <hip/hip_runtime.h>
#include <hip/hip_bf16.h>
#include <cstdint>

#define N_NODES 20000
#define N_EDGES 100000
#define WALK 4
#define FDIM 256
#define HID 64
#define NHEAD 8
#define HR 512
#define OUTD 16

typedef __attribute__((ext_vector_type(8))) short bf16x8;
typedef __attribute__((ext_vector_type(8))) unsigned short u16x8;
typedef __attribute__((ext_vector_type(4))) float f32x4;

__device__ __forceinline__ float b2f(unsigned short u){
  union{float f; unsigned u;} x; x.u = ((unsigned)u)<<16; return x.f;
}
__device__ __forceinline__ unsigned short f2b(float f){
  union{float f; unsigned u;} x; x.f = f;
  unsigned r = x.u + 0x7FFFu + ((x.u>>16)&1u);
  return (unsigned short)(r>>16);
}
__device__ __forceinline__ float sigmoidf_(float v){ return 1.0f/(1.0f+__expf(-v)); }
__device__ __forceinline__ float tanh_c(float v){
  v = fminf(fmaxf(v, -15.f), 15.f);
  const float t2 = __expf(2.0f*v);
  return (t2 - 1.0f) / (t2 + 1.0f);
}

__device__ __forceinline__ void gload16(const void* g, void* l){
  __builtin_amdgcn_global_load_lds(
      (const __attribute__((address_space(1))) void*)(g),
      (__attribute__((address_space(3))) void*)(l),
      16, 0, 0);
}

__device__ __forceinline__ f32x4 mfma16(bf16x8 a, bf16x8 b, f32x4 c){
  return __builtin_amdgcn_mfma_f32_16x16x32_bf16(a, b, c, 0, 0, 0);
}

// ---------------- emb = bf16(x @ W_mlp.T + b_mlp)  (20000x64, linear) ----------------
__launch_bounds__(256)
__global__ void emb_kernel(const float* __restrict__ x,
                           const float* __restrict__ Wm,
                           const float* __restrict__ bm,
                           unsigned short* __restrict__ emb_bf)
{
  __shared__ float xs[4][FDIM];
  const int tid = threadIdx.x;
  const int node0 = blockIdx.x * 4;
  {
    const int row = tid >> 6;
    const int k4  = (tid & 63) * 4;
    *reinterpret_cast<float4*>(&xs[row][k4]) =
      *reinterpret_cast<const float4*>(&x[(size_t)(node0+row)*FDIM + k4]);
  }
  __syncthreads();
  const int nn = tid >> 6, c = tid & 63;
  float acc = bm[c];
  const float* wr = &Wm[c*FDIM];
  #pragma unroll 8
  for (int k=0;k<FDIM;k+=4){
    const float4 w = *reinterpret_cast<const float4*>(&wr[k]);
    acc += xs[nn][k]*w.x + xs[nn][k+1]*w.y + xs[nn][k+2]*w.z + xs[nn][k+3]*w.w;
  }
  emb_bf[(size_t)(node0+nn)*HID + c] = f2b(acc);
}

// ---------------- weight prep (bf16, gate-BLOCKED rows, chunk-swizzle) ----------------
__launch_bounds__(256)
__global__ void prep_kernel(const float* __restrict__ Whh,
                            const float* __restrict__ Wih,
                            const float* __restrict__ Wemb,
                            unsigned short* __restrict__ WhhP,
                            unsigned short* __restrict__ WihP,
                            unsigned short* __restrict__ WembP)
{
  const int t = blockIdx.x*256 + threadIdx.x;
  if (t < 8*192*512){
    const int k = t & 511;
    const int r = (t >> 9) % 192;
    const int db = t / 98304;
    const int G = (r>>6)*HR + db*64 + (r&63);
    const int kg = k >> 6, kw = k & 63;
    const int c = kw >> 3, o = kw & 7;
    const int ksrc = (kg<<6) + (((c ^ (r&7)) << 3) | o);
    WhhP[t] = f2b(Whh[(size_t)G*HR + ksrc]);
  }
  if (t < 8*192*64){
    const int k = t & 63;
    const int r = (t >> 6) % 192;
    const int db = t / 12288;
    const int G = (r>>6)*HR + db*64 + (r&63);
    const int c = k >> 3, o = k & 7;
    const int ksrc = (((c ^ (r&7)) << 3) | o);
    WihP[t] = f2b(Wih[(size_t)G*HID + ksrc]);
  }
  if (t < 64*512){
    const int k = t & 511;
    const int o = t >> 9;
    const int kg = k >> 6, kw = k & 63;
    const int c = kw >> 3, off = kw & 7;
    const int ksrc = (kg<<6) + (((c ^ (o&7)) << 3) | off);
    WembP[t] = f2b(Wemb[(size_t)o*HR + ksrc]);
  }
}

// ---------------- xg: per-node x-gates -> xnP (n-gate + b_ih_n) and h1n (linear) ------
__launch_bounds__(256)
__global__ void xg_kernel(const unsigned short* __restrict__ emb_bf,
                          const unsigned short* __restrict__ WihP,
                          const float* __restrict__ b_ih,
                          const float* __restrict__ b_hh,
                          unsigned short* __restrict__ xnP,
                          unsigned short* __restrict__ h1n)
{
  __shared__ __align__(16) unsigned short As[128*64];
  __shared__ __align__(16) unsigned short Bs[192*64];
  const int tid = threadIdx.x, lane = tid & 63, w = tid >> 6;
  const int tx = lane & 15, ty = lane >> 4;
  const int n0 = blockIdx.x * 128;
  const int db = blockIdx.y;

  #pragma unroll
  for (int j=0;j<4;++j){
    const int flat = j*256 + tid;
    const int row = flat >> 3, c = flat & 7;
    int n = n0 + row; if (n > N_NODES-1) n = N_NODES-1;
    gload16(emb_bf + ((size_t)n*HID + ((c ^ (row&7))<<3)), (char*)As + flat*16);
  }
  #pragma unroll
  for (int j=0;j<6;++j){
    const int flat = j*256 + tid;
    const int row = flat >> 3, c = flat & 7;
    gload16(WihP + ((size_t)(db*192 + row)*HID + c*8), (char*)Bs + flat*16);
  }
  __syncthreads();

  f32x4 acc[2][12];
  #pragma unroll
  for (int m=0;m<2;++m)
    #pragma unroll
    for (int f=0;f<12;++f) acc[m][f] = (f32x4)(0.f);

  auto readFrag = [&](const unsigned short* base, int row, int kk)->bf16x8{
    const int chunk = (kk<<2) + ty;
    return *reinterpret_cast<const bf16x8*>(
        reinterpret_cast<const char*>(base) + (row<<7) + ((chunk ^ (row&7))<<4));
  };
  #pragma unroll
  for (int kk=0; kk<2; ++kk){
    const bf16x8 a0 = readFrag(As, w*32 + tx, kk);
    const bf16x8 a1 = readFrag(As, w*32 + 16 + tx, kk);
    #pragma unroll
    for (int nf=0; nf<12; ++nf){
      const bf16x8 b = readFrag(Bs, nf*16 + tx, kk);
      acc[0][nf] = mfma16(a0, b, acc[0][nf]);
      acc[1][nf] = mfma16(a1, b, acc[1][nf]);
    }
  }

  #pragma unroll
  for (int m=0;m<2;++m){
    #pragma unroll
    for (int reg=0; reg<4; ++reg){
      const int row = w*32 + m*16 + ty*4 + reg;
      const int n = n0 + row;
      if (n < N_NODES){
        #pragma unroll
        for (int fr=0; fr<4; ++fr){
          const int d6 = fr*16 + tx;
          const int dG = db*64 + d6;
          const float xr = acc[m][fr][reg]   + b_ih[dG];
          const float xz = acc[m][4+fr][reg] + b_ih[HR+dG];
          const float xn = acc[m][8+fr][reg] + b_ih[2*HR+dG];
          xnP[((size_t)db*N_NODES + n)*64 + d6] = f2b(xn);
          const float r = sigmoidf_(xr + b_hh[dG]);
          const float z = sigmoidf_(xz + b_hh[HR+dG]);
          const float nn = tanh_c(xn + r*b_hh[2*HR+dG]);
          h1n[(size_t)n*HR + dG] = f2b((1.0f - z)*nn);
        }
      }
    }
  }
}

// ---------------- hgn: per-NODE h-gates GEMM (the step-1 hoist) -----------------------
// hgP[db][node][192] = bf16( h1[node] @ Whh[db-block].T ), gate-blocked cols, no bias.
__launch_bounds__(256)
__global__ void hgn_kernel(const unsigned short* __restrict__ h1n,
                           const unsigned short* __restrict__ WhhP,
                           unsigned short* __restrict__ hgP)
{
  __shared__ __align__(16) unsigned short As[128*64];
  __shared__ __align__(16) unsigned short Bs[192*64];
  const int tid = threadIdx.x, lane = tid & 63, w = tid >> 6;
  const int tx = lane & 15, ty = lane >> 4;
  const int n0 = blockIdx.x * 128;
  const int db = blockIdx.y;

  f32x4 acc[2][12];
  #pragma unroll
  for (int m=0;m<2;++m)
    #pragma unroll
    for (int f=0;f<12;++f) acc[m][f] = (f32x4)(0.f);

  auto stageA = [&](int kt){
    #pragma unroll
    for (int j=0;j<4;++j){
      const int flat = j*256 + tid;
      const int row = flat >> 3, c = flat & 7;
      int n = n0 + row; if (n > N_NODES-1) n = N_NODES-1;
      gload16(h1n + ((size_t)n*HR + kt*64 + ((c ^ (row&7)) << 3)), (char*)As + flat*16);
    }
  };
  auto stageB = [&](int kt){
    #pragma unroll
    for (int j=0;j<6;++j){
      const int flat = j*256 + tid;
      const int row = flat >> 3, c = flat & 7;
      gload16(WhhP + ((size_t)(db*192 + row)*HR + kt*64 + c*8), (char*)Bs + flat*16);
    }
  };
  auto readFrag = [&](const unsigned short* base, int row, int kk)->bf16x8{
    const int chunk = (kk<<2) + ty;
    return *reinterpret_cast<const bf16x8*>(
        reinterpret_cast<const char*>(base) + (row<<7) + ((chunk ^ (row&7))<<4));
  };

  stageA(0); stageB(0);
  #pragma unroll
  for (int kt=0; kt<8; ++kt){
    __syncthreads();
    #pragma unroll
    for (int kk=0; kk<2; ++kk){
      const bf16x8 a0 = readFrag(As, w*32 + tx, kk);
      const bf16x8 a1 = readFrag(As, w*32 + 16 + tx, kk);
      #pragma unroll
      for (int nf=0; nf<12; ++nf){
        const bf16x8 b = readFrag(Bs, nf*16 + tx, kk);
        acc[0][nf] = mfma16(a0, b, acc[0][nf]);
        acc[1][nf] = mfma16(a1, b, acc[1][nf]);
      }
    }
    if (kt < 7){
      __syncthreads();
      stageA(kt+1); stageB(kt+1);
    }
  }

  #pragma unroll
  for (int m=0;m<2;++m){
    #pragma unroll
    for (int reg=0; reg<4; ++reg){
      const int row = w*32 + m*16 + ty*4 + reg;
      const int n = n0 + row;
      if (n < N_NODES){
        #pragma unroll
        for (int nf=0; nf<12; ++nf)
          hgP[((size_t)db*N_NODES + n)*192 + nf*16 + tx] = f2b(acc[m][nf][reg]);
      }
    }
  }
}

// ---------------- step1x: h2 = GRU(h1[n0], x[n1]) with hg gathered per-node -----------
__launch_bounds__(256)
__global__ void step1x_kernel(const unsigned short* __restrict__ emb_bf,
                              const int* __restrict__ idx,
                              const unsigned short* __restrict__ h1n,
                              const unsigned short* __restrict__ hgP,
                              const unsigned short* __restrict__ xnP,
                              const unsigned short* __restrict__ WihP,
                              unsigned short* __restrict__ h_out,
                              const float* __restrict__ b_ih,
                              const float* __restrict__ b_hh)
{
  __shared__ __align__(16) unsigned short As[128*64];   // 16 KB
  __shared__ __align__(16) unsigned short Bs[128*64];   // 16 KB (r,z rows only)
  const int tid = threadIdx.x, lane = tid & 63, w = tid >> 6;
  const int tx = lane & 15, ty = lane >> 4;

  const int bid = blockIdx.x;
  const int sid = (bid & 7)*782 + (bid >> 3);
  const int et = sid >> 3;
  const int db = sid & 7;
  const int e0 = et * 128;

  // stage A = emb[node1] (pre-swizzled gather), B = WihP rows 0..127 (r,z)
  #pragma unroll
  for (int j=0;j<4;++j){
    const int flat = j*256 + tid;
    const int row = flat >> 3, c = flat & 7;
    int e = e0 + row; if (e > N_EDGES-1) e = N_EDGES-1;
    const int n1 = idx[e*WALK + 1];
    gload16(emb_bf + ((size_t)n1*HID + ((c ^ (row&7)) << 3)), (char*)As + flat*16);
  }
  #pragma unroll
  for (int j=0;j<4;++j){
    const int flat = j*256 + tid;
    const int row = flat >> 3, c = flat & 7;
    gload16(WihP + ((size_t)(db*192 + row)*HID + c*8), (char*)Bs + flat*16);
  }
  __syncthreads();

  f32x4 acc[2][8];
  #pragma unroll
  for (int m=0;m<2;++m)
    #pragma unroll
    for (int f=0;f<8;++f) acc[m][f] = (f32x4)(0.f);

  auto readFrag = [&](const unsigned short* base, int row, int kk)->bf16x8{
    const int chunk = (kk<<2) + ty;
    return *reinterpret_cast<const bf16x8*>(
        reinterpret_cast<const char*>(base) + (row<<7) + ((chunk ^ (row&7))<<4));
  };
  #pragma unroll
  for (int kk=0; kk<2; ++kk){
    const bf16x8 a0 = readFrag(As, w*32 + tx, kk);
    const bf16x8 a1 = readFrag(As, w*32 + 16 + tx, kk);
    #pragma unroll
    for (int nf=0; nf<8; ++nf){
      const bf16x8 b = readFrag(Bs, nf*16 + tx, kk);
      acc[0][nf] = mfma16(a0, b, acc[0][nf]);
      acc[1][nf] = mfma16(a1, b, acc[1][nf]);
    }
  }

  float bir[4], biz[4], bhn[4];
  #pragma unroll
  for (int fr=0; fr<4; ++fr){
    const int dG = db*64 + fr*16 + tx;
    bir[fr] = b_ih[dG]      + b_hh[dG];
    biz[fr] = b_ih[HR+dG]   + b_hh[HR+dG];
    bhn[fr] = b_hh[2*HR+dG];
  }

  #pragma unroll
  for (int m=0;m<2;++m){
    #pragma unroll
    for (int reg=0; reg<4; ++reg){
      const int row = w*32 + m*16 + ty*4 + reg;
      const int e = e0 + row;
      if (e < N_EDGES){
        const int n0 = idx[e*WALK];
        const int n1 = idx[e*WALK + 1];
        const size_t hb = ((size_t)db*N_NODES + n0)*192;
        #pragma unroll
        for (int fr=0; fr<4; ++fr){
          const int d6 = fr*16 + tx;
          const int dG = db*64 + d6;
          const float hr = b2f(hgP[hb + d6]);
          const float hz = b2f(hgP[hb + 64 + d6]);
          const float hn = b2f(hgP[hb + 128 + d6]) + bhn[fr];
          const float xn = b2f(xnP[((size_t)db*N_NODES + n1)*64 + d6]);
          const float hold = b2f(h1n[(size_t)n0*HR + dG]);
          const float r  = sigmoidf_(acc[m][fr][reg]   + hr + bir[fr]);
          const float z  = sigmoidf_(acc[m][4+fr][reg] + hz + biz[fr]);
          const float nn = tanh_c(xn + r*hn);
          const float hv = (1.0f - z)*nn + z*hold;
          h_out[(size_t)e*HR + db*64 + (((d6>>3) ^ (e&7))<<3) + (d6&7)] = f2b(hv);
        }
      }
    }
  }
}

// ---------------- GRU steps 2/3 via MFMA: R9 core (4 waves, 40KB, 2-barrier) ----------
template<int STEP, bool SCORE>
__launch_bounds__(256)
__global__ void gru_mfma(const unsigned short* __restrict__ emb_bf,
                         const int* __restrict__ idx,
                         const unsigned short* __restrict__ h_in,   // per-edge swizzled
                         unsigned short* __restrict__ h_out,
                         const unsigned short* __restrict__ WhhP,
                         const unsigned short* __restrict__ WihP,
                         const unsigned short* __restrict__ xnP,
                         const float* __restrict__ b_ih,
                         const float* __restrict__ b_hh,
                         const float* __restrict__ attn,
                         float* __restrict__ a_buf,
                         unsigned int* __restrict__ mmax)
{
  __shared__ __align__(16) unsigned short As[128*64];   // 16 KB
  __shared__ __align__(16) unsigned short Bs[192*64];   // 24 KB

  const int tid = threadIdx.x, lane = tid & 63, w = tid >> 6;
  const int tx = lane & 15, ty = lane >> 4;

  const int bid = blockIdx.x;
  const int sid = (bid & 7)*782 + (bid >> 3);   // bijective XCD swizzle (6256 = 8*782)
  const int et = sid >> 3;
  const int db = sid & 7;
  const int e0 = et * 128;

  int eS[4], nX[4];
  #pragma unroll
  for (int j=0;j<4;++j){
    int e = e0 + ((j*256 + tid) >> 3);
    if (e > N_EDGES-1) e = N_EDGES-1;
    eS[j] = e;
    nX[j] = idx[e*WALK + STEP];
  }

  f32x4 acc[2][12];
  #pragma unroll
  for (int m=0;m<2;++m)
    #pragma unroll
    for (int f=0;f<12;++f) acc[m][f] = (f32x4)(0.f);

  auto stageA = [&](int kt){
    #pragma unroll
    for (int j=0;j<4;++j){
      const int flat = j*256 + tid;
      const int row = flat >> 3, c = flat & 7;
      const unsigned short* src;
      if (kt == 8){
        src = emb_bf + ((size_t)nX[j]*HID + ((c ^ (row&7)) << 3));
      } else {
        src = h_in + ((size_t)eS[j]*HR + kt*64 + c*8);
      }
      gload16(src, (char*)As + flat*16);
    }
  };
  auto stageB = [&](int kt){
    #pragma unroll
    for (int j=0;j<6;++j){
      const int flat = j*256 + tid;
      const int row = flat >> 3, c = flat & 7;
      const unsigned short* src = (kt < 8)
        ? WhhP + ((size_t)(db*192 + row)*HR + kt*64 + c*8)
        : WihP + ((size_t)(db*192 + row)*HID + c*8);
      gload16(src, (char*)Bs + flat*16);
    }
  };
  auto readFrag = [&](const unsigned short* base, int row, int kk)->bf16x8{
    const int chunk = (kk<<2) + ty;
    return *reinterpret_cast<const bf16x8*>(
        reinterpret_cast<const char*>(base) + (row<<7) + ((chunk ^ (row&7))<<4));
  };

  stageA(0); stageB(0);

  #pragma unroll
  for (int kt=0; kt<9; ++kt){
    __syncthreads();
    #pragma unroll
    for (int kk=0; kk<2; ++kk){
      const bf16x8 a0 = readFrag(As, w*32 + tx, kk);
      const bf16x8 a1 = readFrag(As, w*32 + 16 + tx, kk);
      #pragma unroll
      for (int nf=0; nf<12; ++nf){
        if (kt == 8 && nf >= 8) continue;     // x-tile: skip n-gate (xn comes from xnP)
        const bf16x8 b = readFrag(Bs, nf*16 + tx, kk);
        acc[0][nf] = mfma16(a0, b, acc[0][nf]);
        acc[1][nf] = mfma16(a1, b, acc[1][nf]);
      }
    }
    if (kt < 8){
      __syncthreads();
      stageA(kt+1); stageB(kt+1);
    }
  }

  float bir[4], biz[4], bhn[4], atv[4];
  #pragma unroll
  for (int fr=0; fr<4; ++fr){
    const int dG = db*64 + fr*16 + tx;
    bir[fr] = b_ih[dG]      + b_hh[dG];
    biz[fr] = b_ih[HR+dG]   + b_hh[HR+dG];
    bhn[fr] = b_hh[2*HR+dG];
    atv[fr] = SCORE ? attn[dG] : 0.f;
  }

  #pragma unroll
  for (int m=0;m<2;++m){
    #pragma unroll
    for (int reg=0; reg<4; ++reg){
      const int row = w*32 + m*16 + ty*4 + reg;
      const int e = e0 + row;
      float sp = 0.f;
      if (e < N_EDGES){
        const int nodeS = idx[e*WALK + STEP];
        #pragma unroll
        for (int fr=0; fr<4; ++fr){
          const int d6 = fr*16 + tx;
          const float xn = b2f(xnP[((size_t)db*N_NODES + nodeS)*64 + d6]);
          const float hold = b2f(h_in[(size_t)e*HR + db*64 + (((d6>>3) ^ (e&7))<<3) + (d6&7)]);
          const float r  = sigmoidf_(acc[m][fr][reg]   + bir[fr]);
          const float z  = sigmoidf_(acc[m][4+fr][reg] + biz[fr]);
          const float nn = tanh_c(xn + r*(acc[m][8+fr][reg] + bhn[fr]));
          const float hv = (1.0f - z)*nn + z*hold;
          h_out[(size_t)e*HR + db*64 + (((d6>>3) ^ (e&7))<<3) + (d6&7)] = f2b(hv);
          if (SCORE) sp += hv * atv[fr];
        }
      }
      if (SCORE){
        sp += __shfl_xor(sp, 1);
        sp += __shfl_xor(sp, 2);
        sp += __shfl_xor(sp, 4);
        sp += __shfl_xor(sp, 8);
        if (tx == 0 && e < N_EDGES){
          const float a = sp > 0.f ? sp : 0.01f*sp;
          a_buf[e*NHEAD + db] = a;
          const int dst = idx[e*WALK + 3];
          union{float f; unsigned u;} xx; xx.f = a;
          const unsigned key = (xx.u & 0x80000000u) ? ~xx.u : (xx.u | 0x80000000u);
          atomicMax(&mmax[dst*NHEAD + db], key);
        }
      }
    }
  }
}

// ---------------- exp(a-m) + segment sum ----------------
__launch_bounds__(256)
__global__ void ea_kernel(const int* __restrict__ idx,
                          float* __restrict__ a_buf,
                          const unsigned int* __restrict__ mmax,
                          float* __restrict__ ssum)
{
  const int flat = blockIdx.x*256 + threadIdx.x;
  const int e = flat >> 3, h = flat & 7;
  const int dst = idx[e*WALK + 3];
  const unsigned key = mmax[dst*NHEAD + h];
  union{float f; unsigned u;} x;
  x.u = (key & 0x80000000u) ? (key & 0x7FFFFFFFu) : ~key;
  const float ea = __expf(a_buf[flat] - x.f);
  a_buf[flat] = ea;
  atomicAdd(&ssum[dst*NHEAD + h], ea);
}

// ---------------- z[e] = (hT[e]*alpha) @ Wemb.T ; zacc[dst] += z[e] -------------------
__launch_bounds__(256)
__global__ void z_kernel(const unsigned short* __restrict__ hT,
                         const int* __restrict__ idx,
                         const float* __restrict__ ea_buf,
                         const float* __restrict__ ssum,
                         const unsigned short* __restrict__ WembP,
                         float* __restrict__ zacc)
{
  __shared__ __align__(16) char zs[40960];  // Az 32768 + Bz 8192
  char* Az = zs;
  char* Bz = zs + 32768;
  const int tid = threadIdx.x;
  const int lane = tid & 63;
  const int w = tid >> 6;
  const int e0 = blockIdx.x * 256;

  int ej[8], dstj[8];
  #pragma unroll
  for (int j=0;j<8;++j){
    int e = e0 + ((j*256 + tid) >> 3);
    if (e > N_EDGES-1) e = N_EDGES-1;
    ej[j] = e;
    dstj[j] = idx[e*WALK + 3];
  }

  f32x4 acc[4][4];
  #pragma unroll
  for (int m=0;m<4;++m)
    #pragma unroll
    for (int f=0;f<4;++f) acc[m][f] = (f32x4)(0.f);

  auto readFrag = [&](const char* base, int row, int kk)->bf16x8{
    const int chunk = (kk<<2) + (lane>>4);
    return *reinterpret_cast<const bf16x8*>(base + (row<<7) + ((chunk ^ (row&7))<<4));
  };

  #pragma unroll 1
  for (int kt=0; kt<8; ++kt){
    __syncthreads();
    #pragma unroll
    for (int j=0;j<8;++j){
      const int flat = j*256 + tid;
      const int e = ej[j];
      const u16x8 hv = *reinterpret_cast<const u16x8*>(hT + (size_t)e*HR + kt*64 + (flat&7)*8);
      const float al = ea_buf[e*NHEAD + kt] / ssum[dstj[j]*NHEAD + kt];
      union { bf16x8 v; unsigned short s[8]; } o;
      #pragma unroll
      for (int i=0;i<8;++i) o.s[i] = f2b(b2f(hv[i]) * al);
      *reinterpret_cast<bf16x8*>(Az + flat*16) = o.v;
    }
    #pragma unroll
    for (int j=0;j<2;++j){
      const int flat = j*256 + tid;
      const int row = flat >> 3, c = flat & 7;
      gload16(WembP + ((size_t)row*HR + kt*64 + c*8), Bz + ((j*256 + w*64)<<4));
    }
    __syncthreads();
    #pragma unroll
    for (int kk=0; kk<2; ++kk){
      bf16x8 a_[4];
      #pragma unroll
      for (int mf=0; mf<4; ++mf)
        a_[mf] = readFrag(Az, w*64 + mf*16 + (lane&15), kk);
      #pragma unroll
      for (int nf=0; nf<4; ++nf){
        const bf16x8 b_ = readFrag(Bz, nf*16 + (lane&15), kk);
        #pragma unroll
        for (int mf=0; mf<4; ++mf)
          acc[mf][nf] = mfma16(a_[mf], b_, acc[mf][nf]);
      }
    }
  }

  #pragma unroll
  for (int mf=0; mf<4; ++mf){
    #pragma unroll
    for (int reg=0; reg<4; ++reg){
      const int row = w*64 + mf*16 + ((lane>>4)<<2) + reg;
      const int e = e0 + row;
      if (e < N_EDGES){
        const int dst = idx[e*WALK + 3];
        #pragma unroll
        for (int nf=0; nf<4; ++nf){
          const int o = nf*16 + (lane&15);
          atomicAdd(&zacc[(size_t)dst*64 + o], acc[mf][nf][reg]);
        }
      }
    }
  }
}

// ---------------- out = (zacc + b_emb) @ W_last.T + b_last ----------------
__launch_bounds__(256)
__global__ void out2_kernel(const float* __restrict__ zacc,
                            const float* __restrict__ b_emb,
                            const float* __restrict__ W_last,
                            const float* __restrict__ b_last,
                            float* __restrict__ out)
{
  const int flat = blockIdx.x*256 + threadIdx.x;
  if (flat >= N_NODES*OUTD) return;
  const int n = flat >> 4, o = flat & 15;
  float s = b_last[o];
  const float* zr = &zacc[(size_t)n*64];
  const float* wl = &W_last[o*64];
  #pragma unroll
  for (int k=0;k<64;++k) s += (zr[k] + b_emb[k]) * wl[k];
  out[(size_t)n*OUTD + o] = s;
}

// ---------------- launch ----------------
extern "C" void kernel_launch(void* const* d_in, const int* in_sizes, int n_in,
                              void* d_out, int out_size, void* d_ws, size_t ws_size,
                              hipStream_t stream)
{
  (void)in_sizes; (void)n_in; (void)out_size; (void)ws_size;
  const float* x      = (const float*)d_in[0];
  const float* W_mlp  = (const float*)d_in[1];
  const float* b_mlp  = (const float*)d_in[2];
  const float* W_ih   = (const float*)d_in[3];
  const float* W_hh   = (const float*)d_in[4];
  const float* b_ih   = (const float*)d_in[5];
  const float* b_hh   = (const float*)d_in[6];
  const float* attn   = (const float*)d_in[7];
  const float* W_emb  = (const float*)d_in[8];
  const float* b_emb  = (const float*)d_in[9];
  const float* W_last = (const float*)d_in[10];
  const float* b_last = (const float*)d_in[11];
  const int*   idx    = (const int*)d_in[12];
  float* out = (float*)d_out;

  char* ws = (char*)d_ws;
  unsigned short* WhhP   = (unsigned short*)(ws + 0);            //   1,572,864
  unsigned short* WihP   = (unsigned short*)(ws + 1572864);      //     196,608
  unsigned short* WembP  = (unsigned short*)(ws + 1769472);      //      65,536
  unsigned short* emb_bf = (unsigned short*)(ws + 1835008);      //   2,560,000
  unsigned short* xnP    = (unsigned short*)(ws + 4395008);      //  20,480,000
  float*          a_buf  = (float*)(ws + 24875008);              //   3,200,000
  unsigned int*   mmax   = (unsigned int*)(ws + 28075008);       //     640,000
  float*          ssum   = (float*)(ws + 28715008);              //     640,000
  float*          zacc   = (float*)(ws + 29355008);              //   5,120,000
  unsigned short* h_a    = (unsigned short*)(ws + 34475008);     // 102,400,000
  unsigned short* h_b    = (unsigned short*)(ws + 136875008);    // 102,400,000
  // aliases inside h_b (both dead before gru step 2 writes h_b):
  unsigned short* h1n    = h_b;                                  //  20,480,000
  unsigned short* hgP    = (unsigned short*)(ws + 157355008);    //  61,440,000 (h_b+20.48MB)
  // total = 239,275,008 B (R9-proven footprint)

  // zero mmax + ssum + zacc (contiguous 6.4 MB)
  (void)hipMemsetAsync(mmax, 0, 6400000, stream);

  prep_kernel<<<3072, 256, 0, stream>>>(W_hh, W_ih, W_emb, WhhP, WihP, WembP);
  emb_kernel<<<N_NODES/4, 256, 0, stream>>>(x, W_mlp, b_mlp, emb_bf);

  dim3 ngrid((N_NODES + 127)/128, 8);   // 157 x 8
  xg_kernel<<<ngrid, 256, 0, stream>>>(emb_bf, WihP, b_ih, b_hh, xnP, h1n);
  hgn_kernel<<<ngrid, 256, 0, stream>>>(h1n, WhhP, hgP);

  const int NWG = 782*8;  // 6256 blocks: 782 edge-tiles x 8 d-blocks
  step1x_kernel<<<NWG, 256, 0, stream>>>(emb_bf, idx, h1n, hgP, xnP, WihP, h_a, b_ih, b_hh);
  gru_mfma<2,false><<<NWG, 256, 0, stream>>>(emb_bf, idx, h_a, h_b, WhhP, WihP, xnP, b_ih, b_hh, attn, a_buf, mmax);
  gru_mfma<3,true ><<<NWG, 256, 0, stream>>>(emb_bf, idx, h_b, h_a, WhhP, WihP, xnP, b_ih, b_hh, attn, a_buf, mmax);
  // hT (swizzled) in h_a; leaky scores in a_buf; segment max in mmax

  ea_kernel<<<N_EDGES*NHEAD/256, 256, 0, stream>>>(idx, a_buf, mmax, ssum);
  z_kernel<<<391, 256, 0, stream>>>(h_a, idx, a_buf, ssum, WembP, zacc);
  out2_kernel<<<(N_NODES*OUTD+255)/256, 256, 0, stream>>>(zacc, b_emb, W_last, b_last, out);
}

// Round 16
// 1155.577 us; speedup vs baseline: 1.1314x; 1.0129x over previous
//
#include <hip/hip_runtime.h>
#include <hip/hip_bf16.h>
#include <cstdint>

#define N_NODES 20000
#define N_EDGES 100000
#define WALK 4
#define FDIM 256
#define HID 64
#define NHEAD 8
#define HR 512
#define OUTD 16

typedef __attribute__((ext_vector_type(8))) short bf16x8;
typedef __attribute__((ext_vector_type(8))) unsigned short u16x8;
typedef __attribute__((ext_vector_type(4))) float f32x4;

__device__ __forceinline__ float b2f(unsigned short u){
  union{float f; unsigned u;} x; x.u = ((unsigned)u)<<16; return x.f;
}
__device__ __forceinline__ unsigned short f2b(float f){
  union{float f; unsigned u;} x; x.f = f;
  unsigned r = x.u + 0x7FFFu + ((x.u>>16)&1u);
  return (unsigned short)(r>>16);
}
__device__ __forceinline__ float sigmoidf_(float v){ return 1.0f/(1.0f+__expf(-v)); }
__device__ __forceinline__ float tanh_c(float v){
  v = fminf(fmaxf(v, -15.f), 15.f);
  const float t2 = __expf(2.0f*v);
  return (t2 - 1.0f) / (t2 + 1.0f);
}

__device__ __forceinline__ void gload16(const void* g, void* l){
  __builtin_amdgcn_global_load_lds(
      (const __attribute__((address_space(1))) void*)(g),
      (__attribute__((address_space(3))) void*)(l),
      16, 0, 0);
}

__device__ __forceinline__ f32x4 mfma16(bf16x8 a, bf16x8 b, f32x4 c){
  return __builtin_amdgcn_mfma_f32_16x16x32_bf16(a, b, c, 0, 0, 0);
}

// ---------------- emb = bf16(x @ W_mlp.T + b_mlp)  (20000x64, linear) ----------------
__launch_bounds__(256)
__global__ void emb_kernel(const float* __restrict__ x,
                           const float* __restrict__ Wm,
                           const float* __restrict__ bm,
                           unsigned short* __restrict__ emb_bf)
{
  __shared__ float xs[4][FDIM];
  const int tid = threadIdx.x;
  const int node0 = blockIdx.x * 4;
  {
    const int row = tid >> 6;
    const int k4  = (tid & 63) * 4;
    *reinterpret_cast<float4*>(&xs[row][k4]) =
      *reinterpret_cast<const float4*>(&x[(size_t)(node0+row)*FDIM + k4]);
  }
  __syncthreads();
  const int nn = tid >> 6, c = tid & 63;
  float acc = bm[c];
  const float* wr = &Wm[c*FDIM];
  #pragma unroll 8
  for (int k=0;k<FDIM;k+=4){
    const float4 w = *reinterpret_cast<const float4*>(&wr[k]);
    acc += xs[nn][k]*w.x + xs[nn][k+1]*w.y + xs[nn][k+2]*w.z + xs[nn][k+3]*w.w;
  }
  emb_bf[(size_t)(node0+nn)*HID + c] = f2b(acc);
}

// ---------------- weight prep (bf16, gate-BLOCKED rows, chunk-swizzle) ----------------
__launch_bounds__(256)
__global__ void prep_kernel(const float* __restrict__ Whh,
                            const float* __restrict__ Wih,
                            const float* __restrict__ Wemb,
                            unsigned short* __restrict__ WhhP,
                            unsigned short* __restrict__ WihP,
                            unsigned short* __restrict__ WembP)
{
  const int t = blockIdx.x*256 + threadIdx.x;
  if (t < 8*192*512){
    const int k = t & 511;
    const int r = (t >> 9) % 192;
    const int db = t / 98304;
    const int G = (r>>6)*HR + db*64 + (r&63);
    const int kg = k >> 6, kw = k & 63;
    const int c = kw >> 3, o = kw & 7;
    const int ksrc = (kg<<6) + (((c ^ (r&7)) << 3) | o);
    WhhP[t] = f2b(Whh[(size_t)G*HR + ksrc]);
  }
  if (t < 8*192*64){
    const int k = t & 63;
    const int r = (t >> 6) % 192;
    const int db = t / 12288;
    const int G = (r>>6)*HR + db*64 + (r&63);
    const int c = k >> 3, o = k & 7;
    const int ksrc = (((c ^ (r&7)) << 3) | o);
    WihP[t] = f2b(Wih[(size_t)G*HID + ksrc]);
  }
  if (t < 64*512){
    const int k = t & 511;
    const int o = t >> 9;
    const int kg = k >> 6, kw = k & 63;
    const int c = kw >> 3, off = kw & 7;
    const int ksrc = (kg<<6) + (((c ^ (o&7)) << 3) | off);
    WembP[t] = f2b(Wemb[(size_t)o*HR + ksrc]);
  }
}

// ---------------- xg: per-node x-gates -> xnP (n-gate + b_ih_n) and h1n (linear) ------
__launch_bounds__(256)
__global__ void xg_kernel(const unsigned short* __restrict__ emb_bf,
                          const unsigned short* __restrict__ WihP,
                          const float* __restrict__ b_ih,
                          const float* __restrict__ b_hh,
                          unsigned short* __restrict__ xnP,
                          unsigned short* __restrict__ h1n)
{
  __shared__ __align__(16) unsigned short As[128*64];
  __shared__ __align__(16) unsigned short Bs[192*64];
  const int tid = threadIdx.x, lane = tid & 63, w = tid >> 6;
  const int tx = lane & 15, ty = lane >> 4;
  const int n0 = blockIdx.x * 128;
  const int db = blockIdx.y;

  #pragma unroll
  for (int j=0;j<4;++j){
    const int flat = j*256 + tid;
    const int row = flat >> 3, c = flat & 7;
    int n = n0 + row; if (n > N_NODES-1) n = N_NODES-1;
    gload16(emb_bf + ((size_t)n*HID + ((c ^ (row&7))<<3)), (char*)As + flat*16);
  }
  #pragma unroll
  for (int j=0;j<6;++j){
    const int flat = j*256 + tid;
    const int row = flat >> 3, c = flat & 7;
    gload16(WihP + ((size_t)(db*192 + row)*HID + c*8), (char*)Bs + flat*16);
  }
  __syncthreads();

  f32x4 acc[2][12];
  #pragma unroll
  for (int m=0;m<2;++m)
    #pragma unroll
    for (int f=0;f<12;++f) acc[m][f] = (f32x4)(0.f);

  auto readFrag = [&](const unsigned short* base, int row, int kk)->bf16x8{
    const int chunk = (kk<<2) + ty;
    return *reinterpret_cast<const bf16x8*>(
        reinterpret_cast<const char*>(base) + (row<<7) + ((chunk ^ (row&7))<<4));
  };
  #pragma unroll
  for (int kk=0; kk<2; ++kk){
    const bf16x8 a0 = readFrag(As, w*32 + tx, kk);
    const bf16x8 a1 = readFrag(As, w*32 + 16 + tx, kk);
    #pragma unroll
    for (int nf=0; nf<12; ++nf){
      const bf16x8 b = readFrag(Bs, nf*16 + tx, kk);
      acc[0][nf] = mfma16(a0, b, acc[0][nf]);
      acc[1][nf] = mfma16(a1, b, acc[1][nf]);
    }
  }

  #pragma unroll
  for (int m=0;m<2;++m){
    #pragma unroll
    for (int reg=0; reg<4; ++reg){
      const int row = w*32 + m*16 + ty*4 + reg;
      const int n = n0 + row;
      if (n < N_NODES){
        #pragma unroll
        for (int fr=0; fr<4; ++fr){
          const int d6 = fr*16 + tx;
          const int dG = db*64 + d6;
          const float xr = acc[m][fr][reg]   + b_ih[dG];
          const float xz = acc[m][4+fr][reg] + b_ih[HR+dG];
          const float xn = acc[m][8+fr][reg] + b_ih[2*HR+dG];
          xnP[((size_t)db*N_NODES + n)*64 + d6] = f2b(xn);
          const float r = sigmoidf_(xr + b_hh[dG]);
          const float z = sigmoidf_(xz + b_hh[HR+dG]);
          const float nn = tanh_c(xn + r*b_hh[2*HR+dG]);
          h1n[(size_t)n*HR + dG] = f2b((1.0f - z)*nn);
        }
      }
    }
  }
}

// ---------------- hgn: per-NODE h-gates GEMM (the step-1 hoist) -----------------------
__launch_bounds__(256)
__global__ void hgn_kernel(const unsigned short* __restrict__ h1n,
                           const unsigned short* __restrict__ WhhP,
                           unsigned short* __restrict__ hgP)
{
  __shared__ __align__(16) unsigned short As[128*64];
  __shared__ __align__(16) unsigned short Bs[192*64];
  const int tid = threadIdx.x, lane = tid & 63, w = tid >> 6;
  const int tx = lane & 15, ty = lane >> 4;
  const int n0 = blockIdx.x * 128;
  const int db = blockIdx.y;

  f32x4 acc[2][12];
  #pragma unroll
  for (int m=0;m<2;++m)
    #pragma unroll
    for (int f=0;f<12;++f) acc[m][f] = (f32x4)(0.f);

  auto stageA = [&](int kt){
    #pragma unroll
    for (int j=0;j<4;++j){
      const int flat = j*256 + tid;
      const int row = flat >> 3, c = flat & 7;
      int n = n0 + row; if (n > N_NODES-1) n = N_NODES-1;
      gload16(h1n + ((size_t)n*HR + kt*64 + ((c ^ (row&7)) << 3)), (char*)As + flat*16);
    }
  };
  auto stageB = [&](int kt){
    #pragma unroll
    for (int j=0;j<6;++j){
      const int flat = j*256 + tid;
      const int row = flat >> 3, c = flat & 7;
      gload16(WhhP + ((size_t)(db*192 + row)*HR + kt*64 + c*8), (char*)Bs + flat*16);
    }
  };
  auto readFrag = [&](const unsigned short* base, int row, int kk)->bf16x8{
    const int chunk = (kk<<2) + ty;
    return *reinterpret_cast<const bf16x8*>(
        reinterpret_cast<const char*>(base) + (row<<7) + ((chunk ^ (row&7))<<4));
  };

  stageA(0); stageB(0);
  #pragma unroll
  for (int kt=0; kt<8; ++kt){
    __syncthreads();
    #pragma unroll
    for (int kk=0; kk<2; ++kk){
      const bf16x8 a0 = readFrag(As, w*32 + tx, kk);
      const bf16x8 a1 = readFrag(As, w*32 + 16 + tx, kk);
      #pragma unroll
      for (int nf=0; nf<12; ++nf){
        const bf16x8 b = readFrag(Bs, nf*16 + tx, kk);
        acc[0][nf] = mfma16(a0, b, acc[0][nf]);
        acc[1][nf] = mfma16(a1, b, acc[1][nf]);
      }
    }
    if (kt < 7){
      __syncthreads();
      stageA(kt+1); stageB(kt+1);
    }
  }

  #pragma unroll
  for (int m=0;m<2;++m){
    #pragma unroll
    for (int reg=0; reg<4; ++reg){
      const int row = w*32 + m*16 + ty*4 + reg;
      const int n = n0 + row;
      if (n < N_NODES){
        #pragma unroll
        for (int nf=0; nf<12; ++nf)
          hgP[((size_t)db*N_NODES + n)*192 + nf*16 + tx] = f2b(acc[m][nf][reg]);
      }
    }
  }
}

// ---------------- step1x: h2 = GRU(h1[n0], x[n1]) with hg gathered per-node -----------
__launch_bounds__(256)
__global__ void step1x_kernel(const unsigned short* __restrict__ emb_bf,
                              const int* __restrict__ idx,
                              const unsigned short* __restrict__ h1n,
                              const unsigned short* __restrict__ hgP,
                              const unsigned short* __restrict__ xnP,
                              const unsigned short* __restrict__ WihP,
                              unsigned short* __restrict__ h_out,
                              const float* __restrict__ b_ih,
                              const float* __restrict__ b_hh)
{
  __shared__ __align__(16) unsigned short As[128*64];   // 16 KB
  __shared__ __align__(16) unsigned short Bs[128*64];   // 16 KB (r,z rows only)
  const int tid = threadIdx.x, lane = tid & 63, w = tid >> 6;
  const int tx = lane & 15, ty = lane >> 4;

  const int bid = blockIdx.x;
  const int sid = (bid & 7)*782 + (bid >> 3);
  const int et = sid >> 3;
  const int db = sid & 7;
  const int e0 = et * 128;

  #pragma unroll
  for (int j=0;j<4;++j){
    const int flat = j*256 + tid;
    const int row = flat >> 3, c = flat & 7;
    int e = e0 + row; if (e > N_EDGES-1) e = N_EDGES-1;
    const int n1 = idx[e*WALK + 1];
    gload16(emb_bf + ((size_t)n1*HID + ((c ^ (row&7)) << 3)), (char*)As + flat*16);
  }
  #pragma unroll
  for (int j=0;j<4;++j){
    const int flat = j*256 + tid;
    const int row = flat >> 3, c = flat & 7;
    gload16(WihP + ((size_t)(db*192 + row)*HID + c*8), (char*)Bs + flat*16);
  }
  __syncthreads();

  f32x4 acc[2][8];
  #pragma unroll
  for (int m=0;m<2;++m)
    #pragma unroll
    for (int f=0;f<8;++f) acc[m][f] = (f32x4)(0.f);

  auto readFrag = [&](const unsigned short* base, int row, int kk)->bf16x8{
    const int chunk = (kk<<2) + ty;
    return *reinterpret_cast<const bf16x8*>(
        reinterpret_cast<const char*>(base) + (row<<7) + ((chunk ^ (row&7))<<4));
  };
  #pragma unroll
  for (int kk=0; kk<2; ++kk){
    const bf16x8 a0 = readFrag(As, w*32 + tx, kk);
    const bf16x8 a1 = readFrag(As, w*32 + 16 + tx, kk);
    #pragma unroll
    for (int nf=0; nf<8; ++nf){
      const bf16x8 b = readFrag(Bs, nf*16 + tx, kk);
      acc[0][nf] = mfma16(a0, b, acc[0][nf]);
      acc[1][nf] = mfma16(a1, b, acc[1][nf]);
    }
  }

  float bir[4], biz[4], bhn[4];
  #pragma unroll
  for (int fr=0; fr<4; ++fr){
    const int dG = db*64 + fr*16 + tx;
    bir[fr] = b_ih[dG]      + b_hh[dG];
    biz[fr] = b_ih[HR+dG]   + b_hh[HR+dG];
    bhn[fr] = b_hh[2*HR+dG];
  }

  #pragma unroll
  for (int m=0;m<2;++m){
    #pragma unroll
    for (int reg=0; reg<4; ++reg){
      const int row = w*32 + m*16 + ty*4 + reg;
      const int e = e0 + row;
      if (e < N_EDGES){
        const int n0 = idx[e*WALK];
        const int n1 = idx[e*WALK + 1];
        const size_t hb = ((size_t)db*N_NODES + n0)*192;
        #pragma unroll
        for (int fr=0; fr<4; ++fr){
          const int d6 = fr*16 + tx;
          const int dG = db*64 + d6;
          const float hr = b2f(hgP[hb + d6]);
          const float hz = b2f(hgP[hb + 64 + d6]);
          const float hn = b2f(hgP[hb + 128 + d6]) + bhn[fr];
          const float xn = b2f(xnP[((size_t)db*N_NODES + n1)*64 + d6]);
          const float hold = b2f(h1n[(size_t)n0*HR + dG]);
          const float r  = sigmoidf_(acc[m][fr][reg]   + hr + bir[fr]);
          const float z  = sigmoidf_(acc[m][4+fr][reg] + hz + biz[fr]);
          const float nn = tanh_c(xn + r*hn);
          const float hv = (1.0f - z)*nn + z*hold;
          h_out[(size_t)e*HR + db*64 + (((d6>>3) ^ (e&7))<<3) + (d6&7)] = f2b(hv);
        }
      }
    }
  }
}

// ---------------- GRU steps 2/3: B-in-LDS, A DIRECT FROM GLOBAL (per-wave rows) -------
// BM=128, BN=192 gate-blocked, BK=64. kt 0..7 = h, kt 8 = x (n-frags skipped).
// h global layout is chunk-swizzled per edge -> A-fragment = one aligned 16B load at
// position-chunk (logical ^ (e&7)). emb_bf is LINEAR -> kt==8 loads logical chunk
// directly, NO xor (R15 bug: xor applied to linear emb -> permuted r/z gates).
template<int STEP, bool SCORE>
__launch_bounds__(256)
__global__ void gru_mfma(const unsigned short* __restrict__ emb_bf,
                         const int* __restrict__ idx,
                         const unsigned short* __restrict__ h_in,   // per-edge swizzled
                         unsigned short* __restrict__ h_out,
                         const unsigned short* __restrict__ WhhP,
                         const unsigned short* __restrict__ WihP,
                         const unsigned short* __restrict__ xnP,
                         const float* __restrict__ b_ih,
                         const float* __restrict__ b_hh,
                         const float* __restrict__ attn,
                         float* __restrict__ a_buf,
                         unsigned int* __restrict__ mmax)
{
  __shared__ __align__(16) unsigned short Bs[192*64];   // 24 KB

  const int tid = threadIdx.x, lane = tid & 63, w = tid >> 6;
  const int tx = lane & 15, ty = lane >> 4;

  const int bid = blockIdx.x;
  const int sid = (bid & 7)*782 + (bid >> 3);   // bijective XCD swizzle (6256 = 8*782)
  const int et = sid >> 3;
  const int db = sid & 7;
  const int e0 = et * 128;

  // this thread's two A rows (clamped; OOB rows masked at epilogue)
  int eA0 = e0 + w*32 + tx;      if (eA0 > N_EDGES-1) eA0 = N_EDGES-1;
  int eA1 = e0 + w*32 + 16 + tx; if (eA1 > N_EDGES-1) eA1 = N_EDGES-1;
  const int nX0 = idx[eA0*WALK + STEP];
  const int nX1 = idx[eA1*WALK + STEP];

  f32x4 acc[2][12];
  #pragma unroll
  for (int m=0;m<2;++m)
    #pragma unroll
    for (int f=0;f<12;++f) acc[m][f] = (f32x4)(0.f);

  auto stageB = [&](int kt){
    #pragma unroll
    for (int j=0;j<6;++j){
      const int flat = j*256 + tid;
      const int row = flat >> 3, c = flat & 7;
      const unsigned short* src = (kt < 8)
        ? WhhP + ((size_t)(db*192 + row)*HR + kt*64 + c*8)
        : WihP + ((size_t)(db*192 + row)*HID + c*8);
      gload16(src, (char*)Bs + flat*16);
    }
  };
  auto readB = [&](int row, int kk)->bf16x8{
    const int chunk = (kk<<2) + ty;
    return *reinterpret_cast<const bf16x8*>(
        reinterpret_cast<const char*>(Bs) + (row<<7) + ((chunk ^ (row&7))<<4));
  };
  auto loadA = [&](int e, int n, int kt, int kk)->bf16x8{
    const unsigned short* p;
    if (kt == 8){
      // emb is linear: logical chunk directly, no swizzle
      p = emb_bf + ((size_t)n*HID + (((kk<<2)+ty) << 3));
    } else {
      // h is chunk-swizzled per edge: logical chunk at position chunk^(e&7)
      p = h_in + ((size_t)e*HR + kt*64 + (((((kk<<2)+ty) ^ (e&7))) << 3));
    }
    return *reinterpret_cast<const bf16x8*>(p);
  };

  stageB(0);

  #pragma unroll
  for (int kt=0; kt<9; ++kt){
    __syncthreads();            // B(kt) ready
    const bf16x8 a00 = loadA(eA0, nX0, kt, 0);
    const bf16x8 a10 = loadA(eA1, nX1, kt, 0);
    const bf16x8 a01 = loadA(eA0, nX0, kt, 1);
    const bf16x8 a11 = loadA(eA1, nX1, kt, 1);
    #pragma unroll
    for (int kk=0; kk<2; ++kk){
      const bf16x8 a0 = kk ? a01 : a00;
      const bf16x8 a1 = kk ? a11 : a10;
      #pragma unroll
      for (int nf=0; nf<12; ++nf){
        if (kt == 8 && nf >= 8) continue;     // x-tile: skip n-gate (xn from xnP)
        const bf16x8 b = readB(nf*16 + tx, kk);
        acc[0][nf] = mfma16(a0, b, acc[0][nf]);
        acc[1][nf] = mfma16(a1, b, acc[1][nf]);
      }
    }
    if (kt < 8){
      __syncthreads();
      stageB(kt+1);
    }
  }

  float bir[4], biz[4], bhn[4], atv[4];
  #pragma unroll
  for (int fr=0; fr<4; ++fr){
    const int dG = db*64 + fr*16 + tx;
    bir[fr] = b_ih[dG]      + b_hh[dG];
    biz[fr] = b_ih[HR+dG]   + b_hh[HR+dG];
    bhn[fr] = b_hh[2*HR+dG];
    atv[fr] = SCORE ? attn[dG] : 0.f;
  }

  #pragma unroll
  for (int m=0;m<2;++m){
    #pragma unroll
    for (int reg=0; reg<4; ++reg){
      const int row = w*32 + m*16 + ty*4 + reg;
      const int e = e0 + row;
      float sp = 0.f;
      if (e < N_EDGES){
        const int nodeS = idx[e*WALK + STEP];
        #pragma unroll
        for (int fr=0; fr<4; ++fr){
          const int d6 = fr*16 + tx;
          const float xn = b2f(xnP[((size_t)db*N_NODES + nodeS)*64 + d6]);
          const float hold = b2f(h_in[(size_t)e*HR + db*64 + (((d6>>3) ^ (e&7))<<3) + (d6&7)]);
          const float r  = sigmoidf_(acc[m][fr][reg]   + bir[fr]);
          const float z  = sigmoidf_(acc[m][4+fr][reg] + biz[fr]);
          const float nn = tanh_c(xn + r*(acc[m][8+fr][reg] + bhn[fr]));
          const float hv = (1.0f - z)*nn + z*hold;
          h_out[(size_t)e*HR + db*64 + (((d6>>3) ^ (e&7))<<3) + (d6&7)] = f2b(hv);
          if (SCORE) sp += hv * atv[fr];
        }
      }
      if (SCORE){
        sp += __shfl_xor(sp, 1);
        sp += __shfl_xor(sp, 2);
        sp += __shfl_xor(sp, 4);
        sp += __shfl_xor(sp, 8);
        if (tx == 0 && e < N_EDGES){
          const float a = sp > 0.f ? sp : 0.01f*sp;
          a_buf[e*NHEAD + db] = a;
          const int dst = idx[e*WALK + 3];
          union{float f; unsigned u;} xx; xx.f = a;
          const unsigned key = (xx.u & 0x80000000u) ? ~xx.u : (xx.u | 0x80000000u);
          atomicMax(&mmax[dst*NHEAD + db], key);
        }
      }
    }
  }
}

// ---------------- exp(a-m) + segment sum ----------------
__launch_bounds__(256)
__global__ void ea_kernel(const int* __restrict__ idx,
                          float* __restrict__ a_buf,
                          const unsigned int* __restrict__ mmax,
                          float* __restrict__ ssum)
{
  const int flat = blockIdx.x*256 + threadIdx.x;
  const int e = flat >> 3, h = flat & 7;
  const int dst = idx[e*WALK + 3];
  const unsigned key = mmax[dst*NHEAD + h];
  union{float f; unsigned u;} x;
  x.u = (key & 0x80000000u) ? (key & 0x7FFFFFFFu) : ~key;
  const float ea = __expf(a_buf[flat] - x.f);
  a_buf[flat] = ea;
  atomicAdd(&ssum[dst*NHEAD + h], ea);
}

// ---------------- z[e] = (hT[e]*alpha) @ Wemb.T ; zacc[dst] += z[e] -------------------
// 128 edges/block (782 blocks) for better TLP on the atomic tail.
__launch_bounds__(256)
__global__ void z_kernel(const unsigned short* __restrict__ hT,
                         const int* __restrict__ idx,
                         const float* __restrict__ ea_buf,
                         const float* __restrict__ ssum,
                         const unsigned short* __restrict__ WembP,
                         float* __restrict__ zacc)
{
  __shared__ __align__(16) char zs[24576];  // Az 16384 + Bz 8192
  char* Az = zs;
  char* Bz = zs + 16384;
  const int tid = threadIdx.x;
  const int lane = tid & 63;
  const int w = tid >> 6;
  const int e0 = blockIdx.x * 128;

  int ej[4], dstj[4];
  #pragma unroll
  for (int j=0;j<4;++j){
    int e = e0 + ((j*256 + tid) >> 3);
    if (e > N_EDGES-1) e = N_EDGES-1;
    ej[j] = e;
    dstj[j] = idx[e*WALK + 3];
  }

  f32x4 acc[2][4];
  #pragma unroll
  for (int m=0;m<2;++m)
    #pragma unroll
    for (int f=0;f<4;++f) acc[m][f] = (f32x4)(0.f);

  auto readFrag = [&](const char* base, int row, int kk)->bf16x8{
    const int chunk = (kk<<2) + (lane>>4);
    return *reinterpret_cast<const bf16x8*>(base + (row<<7) + ((chunk ^ (row&7))<<4));
  };

  #pragma unroll 1
  for (int kt=0; kt<8; ++kt){
    __syncthreads();
    #pragma unroll
    for (int j=0;j<4;++j){
      const int flat = j*256 + tid;
      const int e = ej[j];
      const u16x8 hv = *reinterpret_cast<const u16x8*>(hT + (size_t)e*HR + kt*64 + (flat&7)*8);
      const float al = ea_buf[e*NHEAD + kt] / ssum[dstj[j]*NHEAD + kt];
      union { bf16x8 v; unsigned short s[8]; } o;
      #pragma unroll
      for (int i=0;i<8;++i) o.s[i] = f2b(b2f(hv[i]) * al);
      *reinterpret_cast<bf16x8*>(Az + flat*16) = o.v;
    }
    #pragma unroll
    for (int j=0;j<2;++j){
      const int flat = j*256 + tid;
      const int row = flat >> 3, c = flat & 7;
      gload16(WembP + ((size_t)row*HR + kt*64 + c*8), Bz + ((j*256 + w*64)<<4));
    }
    __syncthreads();
    #pragma unroll
    for (int kk=0; kk<2; ++kk){
      bf16x8 a_[2];
      #pragma unroll
      for (int mf=0; mf<2; ++mf)
        a_[mf] = readFrag(Az, w*32 + mf*16 + (lane&15), kk);
      #pragma unroll
      for (int nf=0; nf<4; ++nf){
        const bf16x8 b_ = readFrag(Bz, nf*16 + (lane&15), kk);
        #pragma unroll
        for (int mf=0; mf<2; ++mf)
          acc[mf][nf] = mfma16(a_[mf], b_, acc[mf][nf]);
      }
    }
  }

  #pragma unroll
  for (int mf=0; mf<2; ++mf){
    #pragma unroll
    for (int reg=0; reg<4; ++reg){
      const int row = w*32 + mf*16 + ((lane>>4)<<2) + reg;
      const int e = e0 + row;
      if (e < N_EDGES){
        const int dst = idx[e*WALK + 3];
        #pragma unroll
        for (int nf=0; nf<4; ++nf){
          const int o = nf*16 + (lane&15);
          atomicAdd(&zacc[(size_t)dst*64 + o], acc[mf][nf][reg]);
        }
      }
    }
  }
}

// ---------------- out = (zacc + b_emb) @ W_last.T + b_last ----------------
__launch_bounds__(256)
__global__ void out2_kernel(const float* __restrict__ zacc,
                            const float* __restrict__ b_emb,
                            const float* __restrict__ W_last,
                            const float* __restrict__ b_last,
                            float* __restrict__ out)
{
  const int flat = blockIdx.x*256 + threadIdx.x;
  if (flat >= N_NODES*OUTD) return;
  const int n = flat >> 4, o = flat & 15;
  float s = b_last[o];
  const float* zr = &zacc[(size_t)n*64];
  const float* wl = &W_last[o*64];
  #pragma unroll
  for (int k=0;k<64;++k) s += (zr[k] + b_emb[k]) * wl[k];
  out[(size_t)n*OUTD + o] = s;
}

// ---------------- launch ----------------
extern "C" void kernel_launch(void* const* d_in, const int* in_sizes, int n_in,
                              void* d_out, int out_size, void* d_ws, size_t ws_size,
                              hipStream_t stream)
{
  (void)in_sizes; (void)n_in; (void)out_size; (void)ws_size;
  const float* x      = (const float*)d_in[0];
  const float* W_mlp  = (const float*)d_in[1];
  const float* b_mlp  = (const float*)d_in[2];
  const float* W_ih   = (const float*)d_in[3];
  const float* W_hh   = (const float*)d_in[4];
  const float* b_ih   = (const float*)d_in[5];
  const float* b_hh   = (const float*)d_in[6];
  const float* attn   = (const float*)d_in[7];
  const float* W_emb  = (const float*)d_in[8];
  const float* b_emb  = (const float*)d_in[9];
  const float* W_last = (const float*)d_in[10];
  const float* b_last = (const float*)d_in[11];
  const int*   idx    = (const int*)d_in[12];
  float* out = (float*)d_out;

  char* ws = (char*)d_ws;
  unsigned short* WhhP   = (unsigned short*)(ws + 0);            //   1,572,864
  unsigned short* WihP   = (unsigned short*)(ws + 1572864);      //     196,608
  unsigned short* WembP  = (unsigned short*)(ws + 1769472);      //      65,536
  unsigned short* emb_bf = (unsigned short*)(ws + 1835008);      //   2,560,000
  unsigned short* xnP    = (unsigned short*)(ws + 4395008);      //  20,480,000
  float*          a_buf  = (float*)(ws + 24875008);              //   3,200,000
  unsigned int*   mmax   = (unsigned int*)(ws + 28075008);       //     640,000
  float*          ssum   = (float*)(ws + 28715008);              //     640,000
  float*          zacc   = (float*)(ws + 29355008);              //   5,120,000
  unsigned short* h_a    = (unsigned short*)(ws + 34475008);     // 102,400,000
  unsigned short* h_b    = (unsigned short*)(ws + 136875008);    // 102,400,000
  // aliases inside h_b (both dead before gru step 2 writes h_b):
  unsigned short* h1n    = h_b;                                  //  20,480,000
  unsigned short* hgP    = (unsigned short*)(ws + 157355008);    //  61,440,000
  // total = 239,275,008 B

  // zero mmax + ssum + zacc (contiguous 6.4 MB)
  (void)hipMemsetAsync(mmax, 0, 6400000, stream);

  prep_kernel<<<3072, 256, 0, stream>>>(W_hh, W_ih, W_emb, WhhP, WihP, WembP);
  emb_kernel<<<N_NODES/4, 256, 0, stream>>>(x, W_mlp, b_mlp, emb_bf);

  dim3 ngrid((N_NODES + 127)/128, 8);   // 157 x 8
  xg_kernel<<<ngrid, 256, 0, stream>>>(emb_bf, WihP, b_ih, b_hh, xnP, h1n);
  hgn_kernel<<<ngrid, 256, 0, stream>>>(h1n, WhhP, hgP);

  const int NWG = 782*8;  // 6256 blocks: 782 edge-tiles x 8 d-blocks
  step1x_kernel<<<NWG, 256, 0, stream>>>(emb_bf, idx, h1n, hgP, xnP, WihP, h_a, b_ih, b_hh);
  gru_mfma<2,false><<<NWG, 256, 0, stream>>>(emb_bf, idx, h_a, h_b, WhhP, WihP, xnP, b_ih, b_hh, attn, a_buf, mmax);
  gru_mfma<3,true ><<<NWG, 256, 0, stream>>>(emb_bf, idx, h_b, h_a, WhhP, WihP, xnP, b_ih, b_hh, attn, a_buf, mmax);
  // hT (swizzled) in h_a; leaky scores in a_buf; segment max in mmax

  ea_kernel<<<N_EDGES*NHEAD/256, 256, 0, stream>>>(idx, a_buf, mmax, ssum);
  z_kernel<<<782, 256, 0, stream>>>(h_a, idx, a_buf, ssum, WembP, zacc);
  out2_kernel<<<(N_NODES*OUTD+255)/256, 256, 0, stream>>>(zacc, b_emb, W_last, b_last, out);
}

// Round 17
// 1107.614 us; speedup vs baseline: 1.1804x; 1.0433x over previous
//
#include <hip/hip_runtime.h>
#include <hip/hip_bf16.h>
#include <cstdint>

#define N_NODES 20000
#define N_EDGES 100000
#define WALK 4
#define FDIM 256
#define HID 64
#define NHEAD 8
#define HR 512
#define OUTD 16

typedef __attribute__((ext_vector_type(8))) short bf16x8;
typedef __attribute__((ext_vector_type(8))) unsigned short u16x8;
typedef __attribute__((ext_vector_type(4))) float f32x4;

__device__ __forceinline__ float b2f(unsigned short u){
  union{float f; unsigned u;} x; x.u = ((unsigned)u)<<16; return x.f;
}
__device__ __forceinline__ unsigned short f2b(float f){
  union{float f; unsigned u;} x; x.f = f;
  unsigned r = x.u + 0x7FFFu + ((x.u>>16)&1u);
  return (unsigned short)(r>>16);
}
__device__ __forceinline__ float sigmoidf_(float v){ return 1.0f/(1.0f+__expf(-v)); }
__device__ __forceinline__ float tanh_c(float v){
  v = fminf(fmaxf(v, -15.f), 15.f);
  const float t2 = __expf(2.0f*v);
  return (t2 - 1.0f) / (t2 + 1.0f);
}

__device__ __forceinline__ void gload16(const void* g, void* l){
  __builtin_amdgcn_global_load_lds(
      (const __attribute__((address_space(1))) void*)(g),
      (__attribute__((address_space(3))) void*)(l),
      16, 0, 0);
}

__device__ __forceinline__ f32x4 mfma16(bf16x8 a, bf16x8 b, f32x4 c){
  return __builtin_amdgcn_mfma_f32_16x16x32_bf16(a, b, c, 0, 0, 0);
}

// ---------------- emb = bf16(x @ W_mlp.T + b_mlp)  (20000x64, linear) ----------------
__launch_bounds__(256)
__global__ void emb_kernel(const float* __restrict__ x,
                           const float* __restrict__ Wm,
                           const float* __restrict__ bm,
                           unsigned short* __restrict__ emb_bf)
{
  __shared__ float xs[4][FDIM];
  const int tid = threadIdx.x;
  const int node0 = blockIdx.x * 4;
  {
    const int row = tid >> 6;
    const int k4  = (tid & 63) * 4;
    *reinterpret_cast<float4*>(&xs[row][k4]) =
      *reinterpret_cast<const float4*>(&x[(size_t)(node0+row)*FDIM + k4]);
  }
  __syncthreads();
  const int nn = tid >> 6, c = tid & 63;
  float acc = bm[c];
  const float* wr = &Wm[c*FDIM];
  #pragma unroll 8
  for (int k=0;k<FDIM;k+=4){
    const float4 w = *reinterpret_cast<const float4*>(&wr[k]);
    acc += xs[nn][k]*w.x + xs[nn][k+1]*w.y + xs[nn][k+2]*w.z + xs[nn][k+3]*w.w;
  }
  emb_bf[(size_t)(node0+nn)*HID + c] = f2b(acc);
}

// ---------------- weight prep (bf16, gate-BLOCKED rows, chunk-swizzle) ----------------
__launch_bounds__(256)
__global__ void prep_kernel(const float* __restrict__ Whh,
                            const float* __restrict__ Wih,
                            const float* __restrict__ Wemb,
                            unsigned short* __restrict__ WhhP,
                            unsigned short* __restrict__ WihP,
                            unsigned short* __restrict__ WembP)
{
  const int t = blockIdx.x*256 + threadIdx.x;
  if (t < 8*192*512){
    const int k = t & 511;
    const int r = (t >> 9) % 192;
    const int db = t / 98304;
    const int G = (r>>6)*HR + db*64 + (r&63);
    const int kg = k >> 6, kw = k & 63;
    const int c = kw >> 3, o = kw & 7;
    const int ksrc = (kg<<6) + (((c ^ (r&7)) << 3) | o);
    WhhP[t] = f2b(Whh[(size_t)G*HR + ksrc]);
  }
  if (t < 8*192*64){
    const int k = t & 63;
    const int r = (t >> 6) % 192;
    const int db = t / 12288;
    const int G = (r>>6)*HR + db*64 + (r&63);
    const int c = k >> 3, o = k & 7;
    const int ksrc = (((c ^ (r&7)) << 3) | o);
    WihP[t] = f2b(Wih[(size_t)G*HID + ksrc]);
  }
  if (t < 64*512){
    const int k = t & 511;
    const int o = t >> 9;
    const int kg = k >> 6, kw = k & 63;
    const int c = kw >> 3, off = kw & 7;
    const int ksrc = (kg<<6) + (((c ^ (o&7)) << 3) | off);
    WembP[t] = f2b(Wemb[(size_t)o*HR + ksrc]);
  }
}

// ---------------- xg: per-node x-gates -> xnP (n-gate + b_ih_n) and h1n (linear) ------
__launch_bounds__(256)
__global__ void xg_kernel(const unsigned short* __restrict__ emb_bf,
                          const unsigned short* __restrict__ WihP,
                          const float* __restrict__ b_ih,
                          const float* __restrict__ b_hh,
                          unsigned short* __restrict__ xnP,
                          unsigned short* __restrict__ h1n)
{
  __shared__ __align__(16) unsigned short As[128*64];
  __shared__ __align__(16) unsigned short Bs[192*64];
  const int tid = threadIdx.x, lane = tid & 63, w = tid >> 6;
  const int tx = lane & 15, ty = lane >> 4;
  const int n0 = blockIdx.x * 128;
  const int db = blockIdx.y;

  #pragma unroll
  for (int j=0;j<4;++j){
    const int flat = j*256 + tid;
    const int row = flat >> 3, c = flat & 7;
    int n = n0 + row; if (n > N_NODES-1) n = N_NODES-1;
    gload16(emb_bf + ((size_t)n*HID + ((c ^ (row&7))<<3)), (char*)As + flat*16);
  }
  #pragma unroll
  for (int j=0;j<6;++j){
    const int flat = j*256 + tid;
    const int row = flat >> 3, c = flat & 7;
    gload16(WihP + ((size_t)(db*192 + row)*HID + c*8), (char*)Bs + flat*16);
  }
  __syncthreads();

  f32x4 acc[2][12];
  #pragma unroll
  for (int m=0;m<2;++m)
    #pragma unroll
    for (int f=0;f<12;++f) acc[m][f] = (f32x4)(0.f);

  auto readFrag = [&](const unsigned short* base, int row, int kk)->bf16x8{
    const int chunk = (kk<<2) + ty;
    return *reinterpret_cast<const bf16x8*>(
        reinterpret_cast<const char*>(base) + (row<<7) + ((chunk ^ (row&7))<<4));
  };
  #pragma unroll
  for (int kk=0; kk<2; ++kk){
    const bf16x8 a0 = readFrag(As, w*32 + tx, kk);
    const bf16x8 a1 = readFrag(As, w*32 + 16 + tx, kk);
    #pragma unroll
    for (int nf=0; nf<12; ++nf){
      const bf16x8 b = readFrag(Bs, nf*16 + tx, kk);
      acc[0][nf] = mfma16(a0, b, acc[0][nf]);
      acc[1][nf] = mfma16(a1, b, acc[1][nf]);
    }
  }

  #pragma unroll
  for (int m=0;m<2;++m){
    #pragma unroll
    for (int reg=0; reg<4; ++reg){
      const int row = w*32 + m*16 + ty*4 + reg;
      const int n = n0 + row;
      if (n < N_NODES){
        #pragma unroll
        for (int fr=0; fr<4; ++fr){
          const int d6 = fr*16 + tx;
          const int dG = db*64 + d6;
          const float xr = acc[m][fr][reg]   + b_ih[dG];
          const float xz = acc[m][4+fr][reg] + b_ih[HR+dG];
          const float xn = acc[m][8+fr][reg] + b_ih[2*HR+dG];
          xnP[((size_t)db*N_NODES + n)*64 + d6] = f2b(xn);
          const float r = sigmoidf_(xr + b_hh[dG]);
          const float z = sigmoidf_(xz + b_hh[HR+dG]);
          const float nn = tanh_c(xn + r*b_hh[2*HR+dG]);
          h1n[(size_t)n*HR + dG] = f2b((1.0f - z)*nn);
        }
      }
    }
  }
}

// ---------------- hgn: per-NODE h-gates GEMM (the step-1 hoist) -----------------------
__launch_bounds__(256)
__global__ void hgn_kernel(const unsigned short* __restrict__ h1n,
                           const unsigned short* __restrict__ WhhP,
                           unsigned short* __restrict__ hgP)
{
  __shared__ __align__(16) unsigned short As[128*64];
  __shared__ __align__(16) unsigned short Bs[192*64];
  const int tid = threadIdx.x, lane = tid & 63, w = tid >> 6;
  const int tx = lane & 15, ty = lane >> 4;
  const int n0 = blockIdx.x * 128;
  const int db = blockIdx.y;

  f32x4 acc[2][12];
  #pragma unroll
  for (int m=0;m<2;++m)
    #pragma unroll
    for (int f=0;f<12;++f) acc[m][f] = (f32x4)(0.f);

  auto stageA = [&](int kt){
    #pragma unroll
    for (int j=0;j<4;++j){
      const int flat = j*256 + tid;
      const int row = flat >> 3, c = flat & 7;
      int n = n0 + row; if (n > N_NODES-1) n = N_NODES-1;
      gload16(h1n + ((size_t)n*HR + kt*64 + ((c ^ (row&7)) << 3)), (char*)As + flat*16);
    }
  };
  auto stageB = [&](int kt){
    #pragma unroll
    for (int j=0;j<6;++j){
      const int flat = j*256 + tid;
      const int row = flat >> 3, c = flat & 7;
      gload16(WhhP + ((size_t)(db*192 + row)*HR + kt*64 + c*8), (char*)Bs + flat*16);
    }
  };
  auto readFrag = [&](const unsigned short* base, int row, int kk)->bf16x8{
    const int chunk = (kk<<2) + ty;
    return *reinterpret_cast<const bf16x8*>(
        reinterpret_cast<const char*>(base) + (row<<7) + ((chunk ^ (row&7))<<4));
  };

  stageA(0); stageB(0);
  #pragma unroll
  for (int kt=0; kt<8; ++kt){
    __syncthreads();
    #pragma unroll
    for (int kk=0; kk<2; ++kk){
      const bf16x8 a0 = readFrag(As, w*32 + tx, kk);
      const bf16x8 a1 = readFrag(As, w*32 + 16 + tx, kk);
      #pragma unroll
      for (int nf=0; nf<12; ++nf){
        const bf16x8 b = readFrag(Bs, nf*16 + tx, kk);
        acc[0][nf] = mfma16(a0, b, acc[0][nf]);
        acc[1][nf] = mfma16(a1, b, acc[1][nf]);
      }
    }
    if (kt < 7){
      __syncthreads();
      stageA(kt+1); stageB(kt+1);
    }
  }

  #pragma unroll
  for (int m=0;m<2;++m){
    #pragma unroll
    for (int reg=0; reg<4; ++reg){
      const int row = w*32 + m*16 + ty*4 + reg;
      const int n = n0 + row;
      if (n < N_NODES){
        #pragma unroll
        for (int nf=0; nf<12; ++nf)
          hgP[((size_t)db*N_NODES + n)*192 + nf*16 + tx] = f2b(acc[m][nf][reg]);
      }
    }
  }
}

// ---------------- step1x: h2 = GRU(h1[n0], x[n1]) with hg gathered per-node -----------
__launch_bounds__(256)
__global__ void step1x_kernel(const unsigned short* __restrict__ emb_bf,
                              const int* __restrict__ idx,
                              const unsigned short* __restrict__ h1n,
                              const unsigned short* __restrict__ hgP,
                              const unsigned short* __restrict__ xnP,
                              const unsigned short* __restrict__ WihP,
                              unsigned short* __restrict__ h_out,
                              const float* __restrict__ b_ih,
                              const float* __restrict__ b_hh)
{
  __shared__ __align__(16) unsigned short As[128*64];   // 16 KB
  __shared__ __align__(16) unsigned short Bs[128*64];   // 16 KB (r,z rows only)
  const int tid = threadIdx.x, lane = tid & 63, w = tid >> 6;
  const int tx = lane & 15, ty = lane >> 4;

  const int bid = blockIdx.x;
  const int sid = (bid & 7)*782 + (bid >> 3);
  const int et = sid >> 3;
  const int db = sid & 7;
  const int e0 = et * 128;

  #pragma unroll
  for (int j=0;j<4;++j){
    const int flat = j*256 + tid;
    const int row = flat >> 3, c = flat & 7;
    int e = e0 + row; if (e > N_EDGES-1) e = N_EDGES-1;
    const int n1 = idx[e*WALK + 1];
    gload16(emb_bf + ((size_t)n1*HID + ((c ^ (row&7)) << 3)), (char*)As + flat*16);
  }
  #pragma unroll
  for (int j=0;j<4;++j){
    const int flat = j*256 + tid;
    const int row = flat >> 3, c = flat & 7;
    gload16(WihP + ((size_t)(db*192 + row)*HID + c*8), (char*)Bs + flat*16);
  }
  __syncthreads();

  f32x4 acc[2][8];
  #pragma unroll
  for (int m=0;m<2;++m)
    #pragma unroll
    for (int f=0;f<8;++f) acc[m][f] = (f32x4)(0.f);

  auto readFrag = [&](const unsigned short* base, int row, int kk)->bf16x8{
    const int chunk = (kk<<2) + ty;
    return *reinterpret_cast<const bf16x8*>(
        reinterpret_cast<const char*>(base) + (row<<7) + ((chunk ^ (row&7))<<4));
  };
  #pragma unroll
  for (int kk=0; kk<2; ++kk){
    const bf16x8 a0 = readFrag(As, w*32 + tx, kk);
    const bf16x8 a1 = readFrag(As, w*32 + 16 + tx, kk);
    #pragma unroll
    for (int nf=0; nf<8; ++nf){
      const bf16x8 b = readFrag(Bs, nf*16 + tx, kk);
      acc[0][nf] = mfma16(a0, b, acc[0][nf]);
      acc[1][nf] = mfma16(a1, b, acc[1][nf]);
    }
  }

  float bir[4], biz[4], bhn[4];
  #pragma unroll
  for (int fr=0; fr<4; ++fr){
    const int dG = db*64 + fr*16 + tx;
    bir[fr] = b_ih[dG]      + b_hh[dG];
    biz[fr] = b_ih[HR+dG]   + b_hh[HR+dG];
    bhn[fr] = b_hh[2*HR+dG];
  }

  #pragma unroll
  for (int m=0;m<2;++m){
    #pragma unroll
    for (int reg=0; reg<4; ++reg){
      const int row = w*32 + m*16 + ty*4 + reg;
      const int e = e0 + row;
      if (e < N_EDGES){
        const int n0 = idx[e*WALK];
        const int n1 = idx[e*WALK + 1];
        const size_t hb = ((size_t)db*N_NODES + n0)*192;
        #pragma unroll
        for (int fr=0; fr<4; ++fr){
          const int d6 = fr*16 + tx;
          const int dG = db*64 + d6;
          const float hr = b2f(hgP[hb + d6]);
          const float hz = b2f(hgP[hb + 64 + d6]);
          const float hn = b2f(hgP[hb + 128 + d6]) + bhn[fr];
          const float xn = b2f(xnP[((size_t)db*N_NODES + n1)*64 + d6]);
          const float hold = b2f(h1n[(size_t)n0*HR + dG]);
          const float r  = sigmoidf_(acc[m][fr][reg]   + hr + bir[fr]);
          const float z  = sigmoidf_(acc[m][4+fr][reg] + hz + biz[fr]);
          const float nn = tanh_c(xn + r*hn);
          const float hv = (1.0f - z)*nn + z*hold;
          h_out[(size_t)e*HR + db*64 + (((d6>>3) ^ (e&7))<<3) + (d6&7)] = f2b(hv);
        }
      }
    }
  }
}

// ---------------- GRU steps 2/3 via MFMA: R9/R14 staged core (4 waves, 40KB) ----------
// BM=128, BN=192 gate-blocked, BK=64. kt 0..7 = h, kt 8 = x (n-frags skipped).
// Wave w owns rows [w*32,+32), all 12 Nf (complete output rows; R10 lesson).
// Staged A+B via global_load_lds (R16 lesson: A-direct-from-global is slightly worse).
template<int STEP, bool SCORE>
__launch_bounds__(256)
__global__ void gru_mfma(const unsigned short* __restrict__ emb_bf,
                         const int* __restrict__ idx,
                         const unsigned short* __restrict__ h_in,   // per-edge swizzled
                         unsigned short* __restrict__ h_out,
                         const unsigned short* __restrict__ WhhP,
                         const unsigned short* __restrict__ WihP,
                         const unsigned short* __restrict__ xnP,
                         const float* __restrict__ b_ih,
                         const float* __restrict__ b_hh,
                         const float* __restrict__ attn,
                         float* __restrict__ a_buf,
                         unsigned int* __restrict__ mmax)
{
  __shared__ __align__(16) unsigned short As[128*64];   // 16 KB
  __shared__ __align__(16) unsigned short Bs[192*64];   // 24 KB

  const int tid = threadIdx.x, lane = tid & 63, w = tid >> 6;
  const int tx = lane & 15, ty = lane >> 4;

  const int bid = blockIdx.x;
  const int sid = (bid & 7)*782 + (bid >> 3);   // bijective XCD swizzle (6256 = 8*782)
  const int et = sid >> 3;
  const int db = sid & 7;
  const int e0 = et * 128;

  int eS[4], nX[4];
  #pragma unroll
  for (int j=0;j<4;++j){
    int e = e0 + ((j*256 + tid) >> 3);
    if (e > N_EDGES-1) e = N_EDGES-1;
    eS[j] = e;
    nX[j] = idx[e*WALK + STEP];
  }

  f32x4 acc[2][12];
  #pragma unroll
  for (int m=0;m<2;++m)
    #pragma unroll
    for (int f=0;f<12;++f) acc[m][f] = (f32x4)(0.f);

  auto stageA = [&](int kt){
    #pragma unroll
    for (int j=0;j<4;++j){
      const int flat = j*256 + tid;
      const int row = flat >> 3, c = flat & 7;
      const unsigned short* src;
      if (kt == 8){
        src = emb_bf + ((size_t)nX[j]*HID + ((c ^ (row&7)) << 3));
      } else {
        src = h_in + ((size_t)eS[j]*HR + kt*64 + c*8);
      }
      gload16(src, (char*)As + flat*16);
    }
  };
  auto stageB = [&](int kt){
    #pragma unroll
    for (int j=0;j<6;++j){
      const int flat = j*256 + tid;
      const int row = flat >> 3, c = flat & 7;
      const unsigned short* src = (kt < 8)
        ? WhhP + ((size_t)(db*192 + row)*HR + kt*64 + c*8)
        : WihP + ((size_t)(db*192 + row)*HID + c*8);
      gload16(src, (char*)Bs + flat*16);
    }
  };
  auto readFrag = [&](const unsigned short* base, int row, int kk)->bf16x8{
    const int chunk = (kk<<2) + ty;
    return *reinterpret_cast<const bf16x8*>(
        reinterpret_cast<const char*>(base) + (row<<7) + ((chunk ^ (row&7))<<4));
  };

  stageA(0); stageB(0);

  #pragma unroll
  for (int kt=0; kt<9; ++kt){
    __syncthreads();
    #pragma unroll
    for (int kk=0; kk<2; ++kk){
      const bf16x8 a0 = readFrag(As, w*32 + tx, kk);
      const bf16x8 a1 = readFrag(As, w*32 + 16 + tx, kk);
      #pragma unroll
      for (int nf=0; nf<12; ++nf){
        if (kt == 8 && nf >= 8) continue;     // x-tile: skip n-gate (xn comes from xnP)
        const bf16x8 b = readFrag(Bs, nf*16 + tx, kk);
        acc[0][nf] = mfma16(a0, b, acc[0][nf]);
        acc[1][nf] = mfma16(a1, b, acc[1][nf]);
      }
    }
    if (kt < 8){
      __syncthreads();
      stageA(kt+1); stageB(kt+1);
    }
  }

  float bir[4], biz[4], bhn[4], atv[4];
  #pragma unroll
  for (int fr=0; fr<4; ++fr){
    const int dG = db*64 + fr*16 + tx;
    bir[fr] = b_ih[dG]      + b_hh[dG];
    biz[fr] = b_ih[HR+dG]   + b_hh[HR+dG];
    bhn[fr] = b_hh[2*HR+dG];
    atv[fr] = SCORE ? attn[dG] : 0.f;
  }

  #pragma unroll
  for (int m=0;m<2;++m){
    #pragma unroll
    for (int reg=0; reg<4; ++reg){
      const int row = w*32 + m*16 + ty*4 + reg;
      const int e = e0 + row;
      float sp = 0.f;
      if (e < N_EDGES){
        const int nodeS = idx[e*WALK + STEP];
        #pragma unroll
        for (int fr=0; fr<4; ++fr){
          const int d6 = fr*16 + tx;
          const float xn = b2f(xnP[((size_t)db*N_NODES + nodeS)*64 + d6]);
          const float hold = b2f(h_in[(size_t)e*HR + db*64 + (((d6>>3) ^ (e&7))<<3) + (d6&7)]);
          const float r  = sigmoidf_(acc[m][fr][reg]   + bir[fr]);
          const float z  = sigmoidf_(acc[m][4+fr][reg] + biz[fr]);
          const float nn = tanh_c(xn + r*(acc[m][8+fr][reg] + bhn[fr]));
          const float hv = (1.0f - z)*nn + z*hold;
          h_out[(size_t)e*HR + db*64 + (((d6>>3) ^ (e&7))<<3) + (d6&7)] = f2b(hv);
          if (SCORE) sp += hv * atv[fr];
        }
      }
      if (SCORE){
        sp += __shfl_xor(sp, 1);
        sp += __shfl_xor(sp, 2);
        sp += __shfl_xor(sp, 4);
        sp += __shfl_xor(sp, 8);
        if (tx == 0 && e < N_EDGES){
          const float a = sp > 0.f ? sp : 0.01f*sp;
          a_buf[e*NHEAD + db] = a;
          const int dst = idx[e*WALK + 3];
          union{float f; unsigned u;} xx; xx.f = a;
          const unsigned key = (xx.u & 0x80000000u) ? ~xx.u : (xx.u | 0x80000000u);
          atomicMax(&mmax[dst*NHEAD + db], key);
        }
      }
    }
  }
}

// ---------------- exp(a-m) + segment sum ----------------
__launch_bounds__(256)
__global__ void ea_kernel(const int* __restrict__ idx,
                          float* __restrict__ a_buf,
                          const unsigned int* __restrict__ mmax,
                          float* __restrict__ ssum)
{
  const int flat = blockIdx.x*256 + threadIdx.x;
  const int e = flat >> 3, h = flat & 7;
  const int dst = idx[e*WALK + 3];
  const unsigned key = mmax[dst*NHEAD + h];
  union{float f; unsigned u;} x;
  x.u = (key & 0x80000000u) ? (key & 0x7FFFFFFFu) : ~key;
  const float ea = __expf(a_buf[flat] - x.f);
  a_buf[flat] = ea;
  atomicAdd(&ssum[dst*NHEAD + h], ea);
}

// ---------------- z[e] = (hT[e]*alpha) @ Wemb.T ; zacc[dst] += z[e] -------------------
__launch_bounds__(256)
__global__ void z_kernel(const unsigned short* __restrict__ hT,
                         const int* __restrict__ idx,
                         const float* __restrict__ ea_buf,
                         const float* __restrict__ ssum,
                         const unsigned short* __restrict__ WembP,
                         float* __restrict__ zacc)
{
  __shared__ __align__(16) char zs[24576];  // Az 16384 + Bz 8192
  char* Az = zs;
  char* Bz = zs + 16384;
  const int tid = threadIdx.x;
  const int lane = tid & 63;
  const int w = tid >> 6;
  const int e0 = blockIdx.x * 128;

  int ej[4], dstj[4];
  #pragma unroll
  for (int j=0;j<4;++j){
    int e = e0 + ((j*256 + tid) >> 3);
    if (e > N_EDGES-1) e = N_EDGES-1;
    ej[j] = e;
    dstj[j] = idx[e*WALK + 3];
  }

  f32x4 acc[2][4];
  #pragma unroll
  for (int m=0;m<2;++m)
    #pragma unroll
    for (int f=0;f<4;++f) acc[m][f] = (f32x4)(0.f);

  auto readFrag = [&](const char* base, int row, int kk)->bf16x8{
    const int chunk = (kk<<2) + (lane>>4);
    return *reinterpret_cast<const bf16x8*>(base + (row<<7) + ((chunk ^ (row&7))<<4));
  };

  #pragma unroll 1
  for (int kt=0; kt<8; ++kt){
    __syncthreads();
    #pragma unroll
    for (int j=0;j<4;++j){
      const int flat = j*256 + tid;
      const int e = ej[j];
      const u16x8 hv = *reinterpret_cast<const u16x8*>(hT + (size_t)e*HR + kt*64 + (flat&7)*8);
      const float al = ea_buf[e*NHEAD + kt] / ssum[dstj[j]*NHEAD + kt];
      union { bf16x8 v; unsigned short s[8]; } o;
      #pragma unroll
      for (int i=0;i<8;++i) o.s[i] = f2b(b2f(hv[i]) * al);
      *reinterpret_cast<bf16x8*>(Az + flat*16) = o.v;
    }
    #pragma unroll
    for (int j=0;j<2;++j){
      const int flat = j*256 + tid;
      const int row = flat >> 3, c = flat & 7;
      gload16(WembP + ((size_t)row*HR + kt*64 + c*8), Bz + ((j*256 + w*64)<<4));
    }
    __syncthreads();
    #pragma unroll
    for (int kk=0; kk<2; ++kk){
      bf16x8 a_[2];
      #pragma unroll
      for (int mf=0; mf<2; ++mf)
        a_[mf] = readFrag(Az, w*32 + mf*16 + (lane&15), kk);
      #pragma unroll
      for (int nf=0; nf<4; ++nf){
        const bf16x8 b_ = readFrag(Bz, nf*16 + (lane&15), kk);
        #pragma unroll
        for (int mf=0; mf<2; ++mf)
          acc[mf][nf] = mfma16(a_[mf], b_, acc[mf][nf]);
      }
    }
  }

  #pragma unroll
  for (int mf=0; mf<2; ++mf){
    #pragma unroll
    for (int reg=0; reg<4; ++reg){
      const int row = w*32 + mf*16 + ((lane>>4)<<2) + reg;
      const int e = e0 + row;
      if (e < N_EDGES){
        const int dst = idx[e*WALK + 3];
        #pragma unroll
        for (int nf=0; nf<4; ++nf){
          const int o = nf*16 + (lane&15);
          atomicAdd(&zacc[(size_t)dst*64 + o], acc[mf][nf][reg]);
        }
      }
    }
  }
}

// ---------------- out = (zacc + b_emb) @ W_last.T + b_last ----------------
__launch_bounds__(256)
__global__ void out2_kernel(const float* __restrict__ zacc,
                            const float* __restrict__ b_emb,
                            const float* __restrict__ W_last,
                            const float* __restrict__ b_last,
                            float* __restrict__ out)
{
  const int flat = blockIdx.x*256 + threadIdx.x;
  if (flat >= N_NODES*OUTD) return;
  const int n = flat >> 4, o = flat & 15;
  float s = b_last[o];
  const float* zr = &zacc[(size_t)n*64];
  const float* wl = &W_last[o*64];
  #pragma unroll
  for (int k=0;k<64;++k) s += (zr[k] + b_emb[k]) * wl[k];
  out[(size_t)n*OUTD + o] = s;
}

// ---------------- launch ----------------
extern "C" void kernel_launch(void* const* d_in, const int* in_sizes, int n_in,
                              void* d_out, int out_size, void* d_ws, size_t ws_size,
                              hipStream_t stream)
{
  (void)in_sizes; (void)n_in; (void)out_size; (void)ws_size;
  const float* x      = (const float*)d_in[0];
  const float* W_mlp  = (const float*)d_in[1];
  const float* b_mlp  = (const float*)d_in[2];
  const float* W_ih   = (const float*)d_in[3];
  const float* W_hh   = (const float*)d_in[4];
  const float* b_ih   = (const float*)d_in[5];
  const float* b_hh   = (const float*)d_in[6];
  const float* attn   = (const float*)d_in[7];
  const float* W_emb  = (const float*)d_in[8];
  const float* b_emb  = (const float*)d_in[9];
  const float* W_last = (const float*)d_in[10];
  const float* b_last = (const float*)d_in[11];
  const int*   idx    = (const int*)d_in[12];
  float* out = (float*)d_out;

  char* ws = (char*)d_ws;
  unsigned short* WhhP   = (unsigned short*)(ws + 0);            //   1,572,864
  unsigned short* WihP   = (unsigned short*)(ws + 1572864);      //     196,608
  unsigned short* WembP  = (unsigned short*)(ws + 1769472);      //      65,536
  unsigned short* emb_bf = (unsigned short*)(ws + 1835008);      //   2,560,000
  unsigned short* xnP    = (unsigned short*)(ws + 4395008);      //  20,480,000
  float*          a_buf  = (float*)(ws + 24875008);              //   3,200,000
  unsigned int*   mmax   = (unsigned int*)(ws + 28075008);       //     640,000
  float*          ssum   = (float*)(ws + 28715008);              //     640,000
  float*          zacc   = (float*)(ws + 29355008);              //   5,120,000
  unsigned short* h_a    = (unsigned short*)(ws + 34475008);     // 102,400,000
  unsigned short* h_b    = (unsigned short*)(ws + 136875008);    // 102,400,000
  // aliases inside h_b (both dead before gru step 2 writes h_b):
  unsigned short* h1n    = h_b;                                  //  20,480,000
  unsigned short* hgP    = (unsigned short*)(ws + 157355008);    //  61,440,000
  // total = 239,275,008 B

  // zero mmax + ssum + zacc (contiguous 6.4 MB)
  (void)hipMemsetAsync(mmax, 0, 6400000, stream);

  prep_kernel<<<3072, 256, 0, stream>>>(W_hh, W_ih, W_emb, WhhP, WihP, WembP);
  emb_kernel<<<N_NODES/4, 256, 0, stream>>>(x, W_mlp, b_mlp, emb_bf);

  dim3 ngrid((N_NODES + 127)/128, 8);   // 157 x 8
  xg_kernel<<<ngrid, 256, 0, stream>>>(emb_bf, WihP, b_ih, b_hh, xnP, h1n);
  hgn_kernel<<<ngrid, 256, 0, stream>>>(h1n, WhhP, hgP);

  const int NWG = 782*8;  // 6256 blocks: 782 edge-tiles x 8 d-blocks
  step1x_kernel<<<NWG, 256, 0, stream>>>(emb_bf, idx, h1n, hgP, xnP, WihP, h_a, b_ih, b_hh);
  gru_mfma<2,false><<<NWG, 256, 0, stream>>>(emb_bf, idx, h_a, h_b, WhhP, WihP, xnP, b_ih, b_hh, attn, a_buf, mmax);
  gru_mfma<3,true ><<<NWG, 256, 0, stream>>>(emb_bf, idx, h_b, h_a, WhhP, WihP, xnP, b_ih, b_hh, attn, a_buf, mmax);
  // hT (swizzled) in h_a; leaky scores in a_buf; segment max in mmax

  ea_kernel<<<N_EDGES*NHEAD/256, 256, 0, stream>>>(idx, a_buf, mmax, ssum);
  z_kernel<<<782, 256, 0, stream>>>(h_a, idx, a_buf, ssum, WembP, zacc);
  out2_kernel<<<(N_NODES*OUTD+255)/256, 256, 0, stream>>>(zacc, b_emb, W_last, b_last, out);
}